// Round 1
// baseline (661.348 us; speedup 1.0000x reference)
//
#include <hip/hip_runtime.h>
#include <math.h>

#define B_ 4
#define L_ 1024
#define K_ 48
#define EF_ 128
#define NF_ 128
#define NPE_ 16
#define NRBF_ 16
#define MAXREL_ 32
#define EDGE_IN_ 416   // NPE + NRBF*25

#define V_SIZE   (B_*L_*NF_)          // 524288
#define E_OFF    (V_SIZE)
#define E_SIZE   (B_*L_*K_*EF_)       // 25165824
#define EIDX_OFF (E_OFF + E_SIZE)     // 25690112

// atom order: N=0, Ca=1, C=2, O=3, Cb=4. Group 0 = (Ca,Ca), then the 24 PAIRS.
__device__ const int PA_[25] = {1, 0,2,3,4, 1,1,1,1, 0,0,0, 4,4, 3, 0,2,3,4, 2,3,4, 2,3, 2};
__device__ const int PB_[25] = {1, 0,2,3,4, 0,2,3,4, 2,3,4, 2,3, 2, 1,1,1,1, 0,0,0, 4,4, 3};

__device__ __forceinline__ unsigned long long umin64(unsigned long long a, unsigned long long b){
    return a < b ? a : b;
}

// ---------------- V = LN(node_w[label]) ----------------
__global__ __launch_bounds__(128) void v_kernel(const int* __restrict__ labels,
                                                const float* __restrict__ node_w,
                                                const float* __restrict__ g,
                                                const float* __restrict__ bb,
                                                float* __restrict__ out)
{
    int gi = blockIdx.x;
    int f  = threadIdx.x;
    int lbl = labels[gi];
    float v = node_w[lbl*NF_ + f];

    __shared__ float red[2];
    __shared__ float red2[2];
    float s = v;
    #pragma unroll
    for (int m = 1; m < 64; m <<= 1) s += __shfl_xor(s, m, 64);
    if ((f & 63) == 0) red[f >> 6] = s;
    __syncthreads();
    float mu = (red[0] + red[1]) * (1.0f / NF_);
    float d = v - mu;
    float s2 = d * d;
    #pragma unroll
    for (int m = 1; m < 64; m <<= 1) s2 += __shfl_xor(s2, m, 64);
    if ((f & 63) == 0) red2[f >> 6] = s2;
    __syncthreads();
    float var = (red2[0] + red2[1]) * (1.0f / NF_);
    out[gi*NF_ + f] = d * rsqrtf(var + 1e-5f) * g[f] + bb[f];
}

// ---------------- top-K neighbor selection ----------------
__global__ __launch_bounds__(256) void topk_kernel(const float* __restrict__ X,
                                                   const float* __restrict__ mask,
                                                   float* __restrict__ out)
{
    __shared__ float sCa[L_ * 3];
    __shared__ float sM[L_];
    __shared__ float sD[L_];
    __shared__ float wmax[4];
    __shared__ unsigned long long wmin[4];
    __shared__ unsigned long long sSel;
    __shared__ int selIdx[K_];

    int gi = blockIdx.x;
    int b  = gi >> 10;
    int i  = gi & (L_ - 1);
    int tid = threadIdx.x;

    for (int idx = tid; idx < L_ * 3; idx += 256) {
        int j = idx / 3, d = idx - j * 3;
        sCa[idx] = X[(((size_t)((b << 10) + j)) * 4 + 1) * 3 + d];
    }
    for (int j = tid; j < L_; j += 256) sM[j] = mask[(b << 10) + j];
    __syncthreads();

    float cx = sCa[i*3+0], cy = sCa[i*3+1], cz = sCa[i*3+2];
    float mi = sM[i];
    float lmax = 0.0f;
    for (int j = tid; j < L_; j += 256) {
        float dx = cx - sCa[j*3+0];
        float dy = cy - sCa[j*3+1];
        float dz = cz - sCa[j*3+2];
        float dist = sqrtf(dx*dx + dy*dy + dz*dz + 1e-6f);
        float D = mi * sM[j] * dist;
        sD[j] = D;
        lmax = fmaxf(lmax, D);
    }
    #pragma unroll
    for (int m = 1; m < 64; m <<= 1) lmax = fmaxf(lmax, __shfl_xor(lmax, m, 64));
    if ((tid & 63) == 0) wmax[tid >> 6] = lmax;
    __syncthreads();
    float Dmax = fmaxf(fmaxf(wmax[0], wmax[1]), fmaxf(wmax[2], wmax[3]));

    unsigned long long key[4];
    #pragma unroll
    for (int q = 0; q < 4; ++q) {
        int j = tid + q * 256;
        float m2 = mi * sM[j];
        float Dadj = sD[j] + (1.0f - m2) * Dmax;
        key[q] = (((unsigned long long)__float_as_uint(Dadj)) << 32) | (unsigned)j;
    }

    for (int it = 0; it < K_; ++it) {
        unsigned long long kmin = umin64(umin64(key[0], key[1]), umin64(key[2], key[3]));
        #pragma unroll
        for (int m = 1; m < 64; m <<= 1) {
            unsigned long long o = __shfl_xor(kmin, m, 64);
            kmin = umin64(kmin, o);
        }
        if ((tid & 63) == 0) wmin[tid >> 6] = kmin;
        __syncthreads();
        if (tid == 0) {
            unsigned long long mm = umin64(umin64(wmin[0], wmin[1]), umin64(wmin[2], wmin[3]));
            sSel = mm;
            selIdx[it] = (int)(mm & 0xffffffffULL);
        }
        __syncthreads();
        unsigned long long mm = sSel;
        #pragma unroll
        for (int q = 0; q < 4; ++q)
            if (key[q] == mm) key[q] = 0xffffffffffffffffULL;
        __syncthreads();
    }
    if (tid < K_) out[EIDX_OFF + (size_t)gi * K_ + tid] = (float)selIdx[tid];
}

// ---------------- edge features + matmul + LN ----------------
__global__ __launch_bounds__(256) void edge_kernel(const float* __restrict__ X,
                                                   const int* __restrict__ Ridx,
                                                   const int* __restrict__ chains,
                                                   const float* __restrict__ pe_w,
                                                   const float* __restrict__ pe_b,
                                                   const float* __restrict__ edge_w,
                                                   const float* __restrict__ ne_g,
                                                   const float* __restrict__ ne_b,
                                                   float* __restrict__ out)
{
    __shared__ float sAI[5][3];
    __shared__ float sAJ[16][5][3];
    __shared__ int   sJ[16];
    __shared__ int   sDpos[16];
    __shared__ float sDist[16][25];
    __shared__ __align__(16) float sX[16][EDGE_IN_];
    __shared__ __align__(16) float sE[16][EF_];

    int tid = threadIdx.x;
    int e0  = blockIdx.x * 16;
    int gi  = e0 / K_;             // 48 % 16 == 0 -> whole block in one residue row
    int k0  = e0 - gi * K_;
    int b   = gi >> 10;

    if (tid < 16) sJ[tid] = (int)out[EIDX_OFF + (size_t)gi * K_ + k0 + tid];
    __syncthreads();

    if (tid < 17) {
        int r = (tid < 16) ? sJ[tid] : (gi & (L_ - 1));
        const float* xr = X + ((size_t)((b << 10) + r)) * 12;
        float n0=xr[0],  n1=xr[1],  n2=xr[2];
        float a0=xr[3],  a1=xr[4],  a2=xr[5];
        float c0=xr[6],  c1=xr[7],  c2=xr[8];
        float o0=xr[9],  o1=xr[10], o2=xr[11];
        float bx=a0-n0, by=a1-n1, bz=a2-n2;
        float vx=c0-a0, vy=c1-a1, vz=c2-a2;
        float ax = by*vz - bz*vy;
        float ay = bz*vx - bx*vz;
        float az = bx*vy - by*vx;
        float cb0 = -0.58273431f*ax + 0.56802827f*bx - 0.54067466f*vx + a0;
        float cb1 = -0.58273431f*ay + 0.56802827f*by - 0.54067466f*vy + a1;
        float cb2 = -0.58273431f*az + 0.56802827f*bz - 0.54067466f*vz + a2;
        float* dst = (tid < 16) ? &sAJ[tid][0][0] : &sAI[0][0];
        dst[0]=n0;  dst[1]=n1;  dst[2]=n2;
        dst[3]=a0;  dst[4]=a1;  dst[5]=a2;
        dst[6]=c0;  dst[7]=c1;  dst[8]=c2;
        dst[9]=o0;  dst[10]=o1; dst[11]=o2;
        dst[12]=cb0; dst[13]=cb1; dst[14]=cb2;
    }
    if (tid >= 32 && tid < 48) {
        int e = tid - 32;
        int j = sJ[e];
        int off  = Ridx[gi] - Ridx[(b << 10) + j];
        int same = (chains[gi] == chains[(b << 10) + j]);
        int dcl = off + MAXREL_;
        dcl = dcl < 0 ? 0 : (dcl > 2*MAXREL_ ? 2*MAXREL_ : dcl);
        sDpos[e] = same ? dcl : (2*MAXREL_ + 1);
    }
    __syncthreads();

    for (int idx = tid; idx < 16 * 25; idx += 256) {
        int e = idx / 25, g2 = idx - e * 25;
        float dx = sAI[PA_[g2]][0] - sAJ[e][PB_[g2]][0];
        float dy = sAI[PA_[g2]][1] - sAJ[e][PB_[g2]][1];
        float dz = sAI[PA_[g2]][2] - sAJ[e][PB_[g2]][2];
        sDist[e][g2] = sqrtf(dx*dx + dy*dy + dz*dz + 1e-6f);
    }
    __syncthreads();

    for (int idx = tid; idx < 16 * EDGE_IN_; idx += 256) {
        int e = idx / EDGE_IN_;
        int c = idx - e * EDGE_IN_;
        float v;
        if (c < NPE_) {
            v = pe_w[sDpos[e] * NPE_ + c] + pe_b[c];
        } else {
            int g2 = (c - NPE_) >> 4, r = (c - NPE_) & 15;
            float t = (sDist[e][g2] - (2.0f + (20.0f/15.0f) * r)) * 0.8f;
            v = __expf(-t * t);
        }
        sX[e][c] = v;
    }
    __syncthreads();

    // matmul: thread (f, s) accumulates 8 edges for feature f
    int f = tid & 127, s = tid >> 7;
    float acc[8];
    #pragma unroll
    for (int q = 0; q < 8; ++q) acc[q] = 0.0f;

    for (int c = 0; c < EDGE_IN_; c += 4) {
        float w0 = edge_w[(c+0)*EF_ + f];
        float w1 = edge_w[(c+1)*EF_ + f];
        float w2 = edge_w[(c+2)*EF_ + f];
        float w3 = edge_w[(c+3)*EF_ + f];
        #pragma unroll
        for (int e8 = 0; e8 < 8; ++e8) {
            const float4 x4 = *(const float4*)&sX[s*8 + e8][c];
            acc[e8] += x4.x*w0 + x4.y*w1 + x4.z*w2 + x4.w*w3;
        }
    }
    #pragma unroll
    for (int e8 = 0; e8 < 8; ++e8) sE[s*8 + e8][f] = acc[e8];
    __syncthreads();

    // LayerNorm: 16 threads per edge, 8 features each
    int e = tid >> 4, l = tid & 15;
    float vals[8];
    *(float4*)&vals[0] = *(const float4*)&sE[e][l*8];
    *(float4*)&vals[4] = *(const float4*)&sE[e][l*8 + 4];
    float sum = 0.0f;
    #pragma unroll
    for (int q = 0; q < 8; ++q) sum += vals[q];
    #pragma unroll
    for (int m = 1; m < 16; m <<= 1) sum += __shfl_xor(sum, m, 64);
    float mu = sum * (1.0f / 128.0f);
    float s2 = 0.0f;
    #pragma unroll
    for (int q = 0; q < 8; ++q) { float d = vals[q] - mu; s2 += d * d; }
    #pragma unroll
    for (int m = 1; m < 16; m <<= 1) s2 += __shfl_xor(s2, m, 64);
    float rstd = rsqrtf(s2 * (1.0f / 128.0f) + 1e-5f);

    float* dst = out + E_OFF + (size_t)(e0 + e) * EF_ + l * 8;
    #pragma unroll
    for (int q = 0; q < 8; ++q)
        dst[q] = (vals[q] - mu) * rstd * ne_g[l*8 + q] + ne_b[l*8 + q];
}

extern "C" void kernel_launch(void* const* d_in, const int* in_sizes, int n_in,
                              void* d_out, int out_size, void* d_ws, size_t ws_size,
                              hipStream_t stream)
{
    const float* X      = (const float*)d_in[0];
    const float* mask   = (const float*)d_in[1];
    const int*   Ridx   = (const int*)d_in[2];
    const int*   chains = (const int*)d_in[3];
    const int*   memb   = (const int*)d_in[4];
    const float* pe_w   = (const float*)d_in[5];
    const float* pe_b   = (const float*)d_in[6];
    const float* edge_w = (const float*)d_in[7];
    const float* ne_g   = (const float*)d_in[8];
    const float* ne_b   = (const float*)d_in[9];
    const float* node_w = (const float*)d_in[10];
    const float* nn_g   = (const float*)d_in[11];
    const float* nn_b   = (const float*)d_in[12];
    float* out = (float*)d_out;

    v_kernel<<<B_*L_, 128, 0, stream>>>(memb, node_w, nn_g, nn_b, out);
    topk_kernel<<<B_*L_, 256, 0, stream>>>(X, mask, out);
    edge_kernel<<<B_*L_*K_/16, 256, 0, stream>>>(X, Ridx, chains, pe_w, pe_b,
                                                 edge_w, ne_g, ne_b, out);
}

// Round 2
// 271.168 us; speedup vs baseline: 2.4389x; 2.4389x over previous
//
#include <hip/hip_runtime.h>
#include <math.h>

#define B_ 4
#define L_ 1024
#define K_ 48
#define EF_ 128
#define NF_ 128
#define NPE_ 16
#define NRBF_ 16
#define MAXREL_ 32
#define EDGE_IN_ 416   // NPE + NRBF*25

#define V_SIZE   (B_*L_*NF_)          // 524288
#define E_OFF    (V_SIZE)
#define E_SIZE   (B_*L_*K_*EF_)       // 25165824
#define EIDX_OFF (E_OFF + E_SIZE)     // 25690112

#define XB_STRIDE 424                 // bf16 elems per x row (416 + 8 pad)
#define SE_STRIDE 132                 // f32 elems per E row (128 + 4 pad)

typedef __attribute__((ext_vector_type(8))) short bf16x8;
typedef __attribute__((ext_vector_type(4))) float f32x4;

// atom order: N=0, Ca=1, C=2, O=3, Cb=4. Group 0 = (Ca,Ca), then the 24 PAIRS.
__device__ const int PA_[25] = {1, 0,2,3,4, 1,1,1,1, 0,0,0, 4,4, 3, 0,2,3,4, 2,3,4, 2,3, 2};
__device__ const int PB_[25] = {1, 0,2,3,4, 0,2,3,4, 2,3,4, 2,3, 2, 1,1,1,1, 0,0,0, 4,4, 3};

__device__ __forceinline__ unsigned long long umin64(unsigned long long a, unsigned long long b){
    return a < b ? a : b;
}
__device__ __forceinline__ unsigned short f2bf(float f){   // RNE float->bf16
    unsigned u = __float_as_uint(f);
    unsigned r = u + 0x7fffu + ((u >> 16) & 1u);
    return (unsigned short)(r >> 16);
}
__device__ __forceinline__ float bf2f(unsigned short h){
    return __uint_as_float(((unsigned)h) << 16);
}

// ---------------- weight prep: fp32 [416][128] -> bf16 hi/lo transposed [128][416] ----------------
__global__ __launch_bounds__(256) void wprep_kernel(const float* __restrict__ w,
                                                    unsigned short* __restrict__ wh,
                                                    unsigned short* __restrict__ wl)
{
    int idx = blockIdx.x * 256 + threadIdx.x;
    if (idx >= EDGE_IN_ * EF_) return;
    int f = idx & 127;
    int k = idx >> 7;
    float v = w[k * EF_ + f];
    unsigned short h = f2bf(v);
    unsigned short l = f2bf(v - bf2f(h));
    wh[f * EDGE_IN_ + k] = h;
    wl[f * EDGE_IN_ + k] = l;
}

// ---------------- V = LN(node_w[label]) ----------------
__global__ __launch_bounds__(128) void v_kernel(const int* __restrict__ labels,
                                                const float* __restrict__ node_w,
                                                const float* __restrict__ g,
                                                const float* __restrict__ bb,
                                                float* __restrict__ out)
{
    int gi = blockIdx.x;
    int f  = threadIdx.x;
    int lbl = labels[gi];
    float v = node_w[lbl*NF_ + f];

    __shared__ float red[2];
    __shared__ float red2[2];
    float s = v;
    #pragma unroll
    for (int m = 1; m < 64; m <<= 1) s += __shfl_xor(s, m, 64);
    if ((f & 63) == 0) red[f >> 6] = s;
    __syncthreads();
    float mu = (red[0] + red[1]) * (1.0f / NF_);
    float d = v - mu;
    float s2 = d * d;
    #pragma unroll
    for (int m = 1; m < 64; m <<= 1) s2 += __shfl_xor(s2, m, 64);
    if ((f & 63) == 0) red2[f >> 6] = s2;
    __syncthreads();
    float var = (red2[0] + red2[1]) * (1.0f / NF_);
    out[gi*NF_ + f] = d * rsqrtf(var + 1e-5f) * g[f] + bb[f];
}

// ---------------- top-K neighbor selection ----------------
__global__ __launch_bounds__(256) void topk_kernel(const float* __restrict__ X,
                                                   const float* __restrict__ mask,
                                                   float* __restrict__ out)
{
    __shared__ float sCa[L_ * 3];
    __shared__ float sM[L_];
    __shared__ float sD[L_];
    __shared__ float wmax[4];
    __shared__ unsigned long long wmin[4];
    __shared__ unsigned long long sSel;
    __shared__ int selIdx[K_];

    int gi = blockIdx.x;
    int b  = gi >> 10;
    int i  = gi & (L_ - 1);
    int tid = threadIdx.x;

    for (int idx = tid; idx < L_ * 3; idx += 256) {
        int j = idx / 3, d = idx - j * 3;
        sCa[idx] = X[(((size_t)((b << 10) + j)) * 4 + 1) * 3 + d];
    }
    for (int j = tid; j < L_; j += 256) sM[j] = mask[(b << 10) + j];
    __syncthreads();

    float cx = sCa[i*3+0], cy = sCa[i*3+1], cz = sCa[i*3+2];
    float mi = sM[i];
    float lmax = 0.0f;
    for (int j = tid; j < L_; j += 256) {
        float dx = cx - sCa[j*3+0];
        float dy = cy - sCa[j*3+1];
        float dz = cz - sCa[j*3+2];
        float dist = sqrtf(dx*dx + dy*dy + dz*dz + 1e-6f);
        float D = mi * sM[j] * dist;
        sD[j] = D;
        lmax = fmaxf(lmax, D);
    }
    #pragma unroll
    for (int m = 1; m < 64; m <<= 1) lmax = fmaxf(lmax, __shfl_xor(lmax, m, 64));
    if ((tid & 63) == 0) wmax[tid >> 6] = lmax;
    __syncthreads();
    float Dmax = fmaxf(fmaxf(wmax[0], wmax[1]), fmaxf(wmax[2], wmax[3]));

    unsigned long long key[4];
    #pragma unroll
    for (int q = 0; q < 4; ++q) {
        int j = tid + q * 256;
        float m2 = mi * sM[j];
        float Dadj = sD[j] + (1.0f - m2) * Dmax;
        key[q] = (((unsigned long long)__float_as_uint(Dadj)) << 32) | (unsigned)j;
    }

    for (int it = 0; it < K_; ++it) {
        unsigned long long kmin = umin64(umin64(key[0], key[1]), umin64(key[2], key[3]));
        #pragma unroll
        for (int m = 1; m < 64; m <<= 1) {
            unsigned long long o = __shfl_xor(kmin, m, 64);
            kmin = umin64(kmin, o);
        }
        if ((tid & 63) == 0) wmin[tid >> 6] = kmin;
        __syncthreads();
        if (tid == 0) {
            unsigned long long mm = umin64(umin64(wmin[0], wmin[1]), umin64(wmin[2], wmin[3]));
            sSel = mm;
            selIdx[it] = (int)(mm & 0xffffffffULL);
        }
        __syncthreads();
        unsigned long long mm = sSel;
        #pragma unroll
        for (int q = 0; q < 4; ++q)
            if (key[q] == mm) key[q] = 0xffffffffffffffffULL;
        __syncthreads();
    }
    if (tid < K_) out[EIDX_OFF + (size_t)gi * K_ + tid] = (float)selIdx[tid];
}

// ---------------- edge features + MFMA matmul + LN ----------------
// One block = one residue = 48 edges. 4 waves; wave w owns 32 feature cols.
__global__ __launch_bounds__(256) void edge_kernel(const float* __restrict__ X,
                                                   const int* __restrict__ Ridx,
                                                   const int* __restrict__ chains,
                                                   const float* __restrict__ pe_w,
                                                   const float* __restrict__ pe_b,
                                                   const unsigned short* __restrict__ wt_h,
                                                   const unsigned short* __restrict__ wt_l,
                                                   const float* __restrict__ ne_g,
                                                   const float* __restrict__ ne_b,
                                                   float* __restrict__ out)
{
    __shared__ float sAI[16];
    __shared__ float sAJ[K_][16];
    __shared__ int   sJ[K_];
    __shared__ int   sDpos[K_];
    __shared__ float sDist[K_][26];
    __shared__ __align__(16) unsigned char sBuf[K_ * XB_STRIDE * 2];  // xb (bf16) then reused as sE (f32)

    unsigned short* xb = (unsigned short*)sBuf;
    float* sE = (float*)sBuf;

    int tid = threadIdx.x;
    int gi  = blockIdx.x;          // residue index in [0, B*L)
    int b   = gi >> 10;
    int i   = gi & (L_ - 1);

    if (tid < K_) sJ[tid] = (int)out[EIDX_OFF + (size_t)gi * K_ + tid];
    __syncthreads();

    // per-edge neighbor atoms (+Cb) and the i-residue atoms
    if (tid < K_ + 1) {
        int r = (tid < K_) ? sJ[tid] : i;
        const float* xr = X + ((size_t)((b << 10) + r)) * 12;
        float n0=xr[0],  n1=xr[1],  n2=xr[2];
        float a0=xr[3],  a1=xr[4],  a2=xr[5];
        float c0=xr[6],  c1=xr[7],  c2=xr[8];
        float o0=xr[9],  o1=xr[10], o2=xr[11];
        float bx=a0-n0, by=a1-n1, bz=a2-n2;
        float vx=c0-a0, vy=c1-a1, vz=c2-a2;
        float ax = by*vz - bz*vy;
        float ay = bz*vx - bx*vz;
        float az = bx*vy - by*vx;
        float cb0 = -0.58273431f*ax + 0.56802827f*bx - 0.54067466f*vx + a0;
        float cb1 = -0.58273431f*ay + 0.56802827f*by - 0.54067466f*vy + a1;
        float cb2 = -0.58273431f*az + 0.56802827f*bz - 0.54067466f*vz + a2;
        float* dst = (tid < K_) ? &sAJ[tid][0] : &sAI[0];
        dst[0]=n0;  dst[1]=n1;  dst[2]=n2;
        dst[3]=a0;  dst[4]=a1;  dst[5]=a2;
        dst[6]=c0;  dst[7]=c1;  dst[8]=c2;
        dst[9]=o0;  dst[10]=o1; dst[11]=o2;
        dst[12]=cb0; dst[13]=cb1; dst[14]=cb2;
    }
    if (tid >= 64 && tid < 64 + K_) {
        int e = tid - 64;
        int j = sJ[e];
        int off  = Ridx[gi] - Ridx[(b << 10) + j];
        int same = (chains[gi] == chains[(b << 10) + j]);
        int dcl = off + MAXREL_;
        dcl = dcl < 0 ? 0 : (dcl > 2*MAXREL_ ? 2*MAXREL_ : dcl);
        sDpos[e] = same ? dcl : (2*MAXREL_ + 1);
    }
    __syncthreads();

    for (int idx = tid; idx < K_ * 25; idx += 256) {
        int e = idx / 25, g2 = idx - e * 25;
        float dx = sAI[PA_[g2]*3+0] - sAJ[e][PB_[g2]*3+0];
        float dy = sAI[PA_[g2]*3+1] - sAJ[e][PB_[g2]*3+1];
        float dz = sAI[PA_[g2]*3+2] - sAJ[e][PB_[g2]*3+2];
        sDist[e][g2] = sqrtf(dx*dx + dy*dy + dz*dz + 1e-6f);
    }
    __syncthreads();

    // fill x (bf16), 2 features per thread-step
    for (int idx = tid; idx < K_ * (EDGE_IN_ / 2); idx += 256) {
        int e  = idx / (EDGE_IN_ / 2);
        int cc = (idx - e * (EDGE_IN_ / 2)) * 2;
        float v0, v1;
        if (cc < NPE_) {
            int dp = sDpos[e];
            v0 = pe_w[dp * NPE_ + cc]     + pe_b[cc];
            v1 = pe_w[dp * NPE_ + cc + 1] + pe_b[cc + 1];
        } else {
            int g2 = (cc - NPE_) >> 4;
            int r0 = (cc - NPE_) & 15;
            float dist = sDist[e][g2];
            float t0 = (dist - (2.0f + (20.0f/15.0f) * r0)) * 0.8f;
            float t1 = (dist - (2.0f + (20.0f/15.0f) * (r0+1))) * 0.8f;
            v0 = __expf(-t0 * t0);
            v1 = __expf(-t1 * t1);
        }
        unsigned pk = (unsigned)f2bf(v0) | ((unsigned)f2bf(v1) << 16);
        *(unsigned*)&xb[e * XB_STRIDE + cc] = pk;
    }
    __syncthreads();

    // ---- MFMA GEMM: [48 x 416] x [416 x 128] ----
    int wv = tid >> 6;
    int ln = tid & 63;
    int lr = ln & 15;
    int lg = ln >> 4;

    f32x4 acc[3][2];
    #pragma unroll
    for (int rf = 0; rf < 3; ++rf)
        #pragma unroll
        for (int cf = 0; cf < 2; ++cf)
            acc[rf][cf] = (f32x4){0.0f, 0.0f, 0.0f, 0.0f};

    const unsigned short* wbase_h0 = wt_h + (size_t)(wv*32 + lr) * EDGE_IN_ + lg*8;
    const unsigned short* wbase_h1 = wt_h + (size_t)(wv*32 + 16 + lr) * EDGE_IN_ + lg*8;
    const unsigned short* wbase_l0 = wt_l + (size_t)(wv*32 + lr) * EDGE_IN_ + lg*8;
    const unsigned short* wbase_l1 = wt_l + (size_t)(wv*32 + 16 + lr) * EDGE_IN_ + lg*8;

    #pragma unroll 1
    for (int ks = 0; ks < EDGE_IN_ / 32; ++ks) {
        int k0 = ks * 32;
        bf16x8 a[3], bh[2], bl[2];
        #pragma unroll
        for (int rf = 0; rf < 3; ++rf)
            a[rf] = *(const bf16x8*)&xb[(rf*16 + lr) * XB_STRIDE + k0 + lg*8];
        bh[0] = *(const bf16x8*)(wbase_h0 + k0);
        bh[1] = *(const bf16x8*)(wbase_h1 + k0);
        bl[0] = *(const bf16x8*)(wbase_l0 + k0);
        bl[1] = *(const bf16x8*)(wbase_l1 + k0);
        #pragma unroll
        for (int rf = 0; rf < 3; ++rf) {
            #pragma unroll
            for (int cf = 0; cf < 2; ++cf) {
                acc[rf][cf] = __builtin_amdgcn_mfma_f32_16x16x32_bf16(a[rf], bh[cf], acc[rf][cf], 0, 0, 0);
                acc[rf][cf] = __builtin_amdgcn_mfma_f32_16x16x32_bf16(a[rf], bl[cf], acc[rf][cf], 0, 0, 0);
            }
        }
    }
    __syncthreads();   // all waves done reading xb; sBuf becomes sE

    #pragma unroll
    for (int rf = 0; rf < 3; ++rf)
        #pragma unroll
        for (int cf = 0; cf < 2; ++cf)
            #pragma unroll
            for (int r = 0; r < 4; ++r) {
                int row = rf*16 + lg*4 + r;
                int col = wv*32 + cf*16 + lr;
                sE[row * SE_STRIDE + col] = acc[rf][cf][r];
            }
    __syncthreads();

    // LayerNorm: 16 lanes per edge, 8 features per lane; 3 passes of 16 edges
    int l16 = tid & 15;
    float gv[8], bv[8];
    #pragma unroll
    for (int q = 0; q < 8; ++q) { gv[q] = ne_g[l16*8 + q]; bv[q] = ne_b[l16*8 + q]; }

    for (int p = 0; p < 3; ++p) {
        int e = p*16 + (tid >> 4);
        float vals[8];
        #pragma unroll
        for (int q = 0; q < 8; ++q) vals[q] = sE[e * SE_STRIDE + l16*8 + q];
        float sum = 0.0f;
        #pragma unroll
        for (int q = 0; q < 8; ++q) sum += vals[q];
        #pragma unroll
        for (int m = 1; m < 16; m <<= 1) sum += __shfl_xor(sum, m, 64);
        float mu = sum * (1.0f / 128.0f);
        float s2 = 0.0f;
        #pragma unroll
        for (int q = 0; q < 8; ++q) { float d = vals[q] - mu; s2 += d * d; }
        #pragma unroll
        for (int m = 1; m < 16; m <<= 1) s2 += __shfl_xor(s2, m, 64);
        float rstd = rsqrtf(s2 * (1.0f / 128.0f) + 1e-5f);

        float* dst = out + E_OFF + (size_t)(gi * K_ + e) * EF_ + l16*8;
        #pragma unroll
        for (int q = 0; q < 8; ++q)
            dst[q] = (vals[q] - mu) * rstd * gv[q] + bv[q];
    }
}

extern "C" void kernel_launch(void* const* d_in, const int* in_sizes, int n_in,
                              void* d_out, int out_size, void* d_ws, size_t ws_size,
                              hipStream_t stream)
{
    const float* X      = (const float*)d_in[0];
    const float* mask   = (const float*)d_in[1];
    const int*   Ridx   = (const int*)d_in[2];
    const int*   chains = (const int*)d_in[3];
    const int*   memb   = (const int*)d_in[4];
    const float* pe_w   = (const float*)d_in[5];
    const float* pe_b   = (const float*)d_in[6];
    const float* edge_w = (const float*)d_in[7];
    const float* ne_g   = (const float*)d_in[8];
    const float* ne_b   = (const float*)d_in[9];
    const float* node_w = (const float*)d_in[10];
    const float* nn_g   = (const float*)d_in[11];
    const float* nn_b   = (const float*)d_in[12];
    float* out = (float*)d_out;

    unsigned short* wt_h = (unsigned short*)d_ws;
    unsigned short* wt_l = wt_h + (size_t)EDGE_IN_ * EF_;

    wprep_kernel<<<(EDGE_IN_*EF_ + 255)/256, 256, 0, stream>>>(edge_w, wt_h, wt_l);
    v_kernel<<<B_*L_, 128, 0, stream>>>(memb, node_w, nn_g, nn_b, out);
    topk_kernel<<<B_*L_, 256, 0, stream>>>(X, mask, out);
    edge_kernel<<<B_*L_, 256, 0, stream>>>(X, Ridx, chains, pe_w, pe_b,
                                           wt_h, wt_l, ne_g, ne_b, out);
}

// Round 3
// 247.067 us; speedup vs baseline: 2.6768x; 1.0975x over previous
//
#include <hip/hip_runtime.h>
#include <math.h>

#define B_ 4
#define L_ 1024
#define K_ 48
#define EF_ 128
#define NF_ 128
#define NPE_ 16
#define NRBF_ 16
#define MAXREL_ 32
#define EDGE_IN_ 416   // NPE + NRBF*25

#define V_SIZE   (B_*L_*NF_)          // 524288
#define E_OFF    (V_SIZE)
#define E_SIZE   (B_*L_*K_*EF_)       // 25165824
#define EIDX_OFF (E_OFF + E_SIZE)     // 25690112

#define XB_STRIDE 424                 // bf16 elems per x row (416 + 8 pad)
#define SE_STRIDE 132                 // f32 elems per E row (128 + 4 pad)

typedef __attribute__((ext_vector_type(8))) short bf16x8;
typedef __attribute__((ext_vector_type(4))) float f32x4;

// atom order: N=0, Ca=1, C=2, O=3, Cb=4. Group 0 = (Ca,Ca), then the 24 PAIRS.
__device__ const int PA_[25] = {1, 0,2,3,4, 1,1,1,1, 0,0,0, 4,4, 3, 0,2,3,4, 2,3,4, 2,3, 2};
__device__ const int PB_[25] = {1, 0,2,3,4, 0,2,3,4, 2,3,4, 2,3, 2, 1,1,1,1, 0,0,0, 4,4, 3};

__device__ __forceinline__ unsigned short f2bf(float f){   // RNE float->bf16
    unsigned u = __float_as_uint(f);
    unsigned r = u + 0x7fffu + ((u >> 16) & 1u);
    return (unsigned short)(r >> 16);
}
__device__ __forceinline__ float bf2f(unsigned short h){
    return __uint_as_float(((unsigned)h) << 16);
}

// ---------------- weight prep: fp32 [416][128] -> bf16 hi/lo transposed [128][416] ----------------
__global__ __launch_bounds__(256) void wprep_kernel(const float* __restrict__ w,
                                                    unsigned short* __restrict__ wh,
                                                    unsigned short* __restrict__ wl)
{
    int idx = blockIdx.x * 256 + threadIdx.x;
    if (idx >= EDGE_IN_ * EF_) return;
    int f = idx & 127;
    int k = idx >> 7;
    float v = w[k * EF_ + f];
    unsigned short h = f2bf(v);
    unsigned short l = f2bf(v - bf2f(h));
    wh[f * EDGE_IN_ + k] = h;
    wl[f * EDGE_IN_ + k] = l;
}

// ---------------- V = LN(node_w[label]) ----------------
__global__ __launch_bounds__(128) void v_kernel(const int* __restrict__ labels,
                                                const float* __restrict__ node_w,
                                                const float* __restrict__ g,
                                                const float* __restrict__ bb,
                                                float* __restrict__ out)
{
    int gi = blockIdx.x;
    int f  = threadIdx.x;
    int lbl = labels[gi];
    float v = node_w[lbl*NF_ + f];

    __shared__ float red[2];
    __shared__ float red2[2];
    float s = v;
    #pragma unroll
    for (int m = 1; m < 64; m <<= 1) s += __shfl_xor(s, m, 64);
    if ((f & 63) == 0) red[f >> 6] = s;
    __syncthreads();
    float mu = (red[0] + red[1]) * (1.0f / NF_);
    float d = v - mu;
    float s2 = d * d;
    #pragma unroll
    for (int m = 1; m < 64; m <<= 1) s2 += __shfl_xor(s2, m, 64);
    if ((f & 63) == 0) red2[f >> 6] = s2;
    __syncthreads();
    float var = (red2[0] + red2[1]) * (1.0f / NF_);
    out[gi*NF_ + f] = d * rsqrtf(var + 1e-5f) * g[f] + bb[f];
}

// ---------------- top-K neighbor selection via full LDS bitonic sort ----------------
__global__ __launch_bounds__(256) void topk_kernel(const float* __restrict__ X,
                                                   const float* __restrict__ mask,
                                                   float* __restrict__ out)
{
    // keys[] (8KB) aliases the sCa staging buffer (12KB) — sCa is dead once
    // distances are computed.
    __shared__ __align__(16) unsigned char sMem[L_ * 3 * 4];
    __shared__ float sM[L_];
    __shared__ float sD[L_];
    __shared__ float wmax[4];

    float* sCa = (float*)sMem;
    unsigned long long* keys = (unsigned long long*)sMem;

    int gi = blockIdx.x;
    int b  = gi >> 10;
    int i  = gi & (L_ - 1);
    int tid = threadIdx.x;

    for (int idx = tid; idx < L_ * 3; idx += 256) {
        int j = idx / 3, d = idx - j * 3;
        sCa[idx] = X[(((size_t)((b << 10) + j)) * 4 + 1) * 3 + d];
    }
    for (int j = tid; j < L_; j += 256) sM[j] = mask[(b << 10) + j];
    __syncthreads();

    float cx = sCa[i*3+0], cy = sCa[i*3+1], cz = sCa[i*3+2];
    float mi = sM[i];
    float lmax = 0.0f;
    #pragma unroll
    for (int q = 0; q < 4; ++q) {
        int j = tid + q * 256;
        float dx = cx - sCa[j*3+0];
        float dy = cy - sCa[j*3+1];
        float dz = cz - sCa[j*3+2];
        float dist = sqrtf(dx*dx + dy*dy + dz*dz + 1e-6f);
        float D = mi * sM[j] * dist;
        sD[j] = D;
        lmax = fmaxf(lmax, D);
    }
    #pragma unroll
    for (int m = 1; m < 64; m <<= 1) lmax = fmaxf(lmax, __shfl_xor(lmax, m, 64));
    if ((tid & 63) == 0) wmax[tid >> 6] = lmax;
    __syncthreads();          // also: all sCa reads done before keys overwrite
    float Dmax = fmaxf(fmaxf(wmax[0], wmax[1]), fmaxf(wmax[2], wmax[3]));

    #pragma unroll
    for (int q = 0; q < 4; ++q) {
        int j = tid + q * 256;
        float m2 = mi * sM[j];
        float Dadj = sD[j] + (1.0f - m2) * Dmax;
        keys[j] = (((unsigned long long)__float_as_uint(Dadj)) << 32) | (unsigned)j;
    }

    // ascending bitonic sort of keys[0..1023]
    for (unsigned k = 2; k <= (unsigned)L_; k <<= 1) {
        for (unsigned j = k >> 1; j > 0; j >>= 1) {
            __syncthreads();
            #pragma unroll
            for (int q = 0; q < 4; ++q) {
                int idx = tid + q * 256;
                int l = idx ^ (int)j;
                if (l > idx) {
                    unsigned long long a = keys[idx];
                    unsigned long long c = keys[l];
                    bool asc = ((idx & (int)k) == 0);
                    if ((a > c) == asc) { keys[idx] = c; keys[l] = a; }
                }
            }
        }
    }
    __syncthreads();

    if (tid < K_)
        out[EIDX_OFF + (size_t)gi * K_ + tid] = (float)(unsigned)(keys[tid] & 0xffffffffULL);
}

// ---------------- edge features + MFMA matmul + LN ----------------
// One block = one residue = 48 edges. 4 waves; wave w owns 32 feature cols.
__global__ __launch_bounds__(256) void edge_kernel(const float* __restrict__ X,
                                                   const int* __restrict__ Ridx,
                                                   const int* __restrict__ chains,
                                                   const float* __restrict__ pe_w,
                                                   const float* __restrict__ pe_b,
                                                   const unsigned short* __restrict__ wt_h,
                                                   const unsigned short* __restrict__ wt_l,
                                                   const float* __restrict__ ne_g,
                                                   const float* __restrict__ ne_b,
                                                   float* __restrict__ out)
{
    __shared__ float sAI[16];
    __shared__ float sAJ[K_][16];
    __shared__ int   sJ[K_];
    __shared__ int   sDpos[K_];
    __shared__ float sDist[K_][26];
    __shared__ __align__(16) unsigned char sBuf[K_ * XB_STRIDE * 2];  // xb (bf16) then reused as sE (f32)

    unsigned short* xb = (unsigned short*)sBuf;
    float* sE = (float*)sBuf;

    int tid = threadIdx.x;
    int gi  = blockIdx.x;          // residue index in [0, B*L)
    int b   = gi >> 10;
    int i   = gi & (L_ - 1);

    if (tid < K_) sJ[tid] = (int)out[EIDX_OFF + (size_t)gi * K_ + tid];
    __syncthreads();

    // per-edge neighbor atoms (+Cb) and the i-residue atoms
    if (tid < K_ + 1) {
        int r = (tid < K_) ? sJ[tid] : i;
        const float* xr = X + ((size_t)((b << 10) + r)) * 12;
        float n0=xr[0],  n1=xr[1],  n2=xr[2];
        float a0=xr[3],  a1=xr[4],  a2=xr[5];
        float c0=xr[6],  c1=xr[7],  c2=xr[8];
        float o0=xr[9],  o1=xr[10], o2=xr[11];
        float bx=a0-n0, by=a1-n1, bz=a2-n2;
        float vx=c0-a0, vy=c1-a1, vz=c2-a2;
        float ax = by*vz - bz*vy;
        float ay = bz*vx - bx*vz;
        float az = bx*vy - by*vx;
        float cb0 = -0.58273431f*ax + 0.56802827f*bx - 0.54067466f*vx + a0;
        float cb1 = -0.58273431f*ay + 0.56802827f*by - 0.54067466f*vy + a1;
        float cb2 = -0.58273431f*az + 0.56802827f*bz - 0.54067466f*vz + a2;
        float* dst = (tid < K_) ? &sAJ[tid][0] : &sAI[0];
        dst[0]=n0;  dst[1]=n1;  dst[2]=n2;
        dst[3]=a0;  dst[4]=a1;  dst[5]=a2;
        dst[6]=c0;  dst[7]=c1;  dst[8]=c2;
        dst[9]=o0;  dst[10]=o1; dst[11]=o2;
        dst[12]=cb0; dst[13]=cb1; dst[14]=cb2;
    }
    if (tid >= 64 && tid < 64 + K_) {
        int e = tid - 64;
        int j = sJ[e];
        int off  = Ridx[gi] - Ridx[(b << 10) + j];
        int same = (chains[gi] == chains[(b << 10) + j]);
        int dcl = off + MAXREL_;
        dcl = dcl < 0 ? 0 : (dcl > 2*MAXREL_ ? 2*MAXREL_ : dcl);
        sDpos[e] = same ? dcl : (2*MAXREL_ + 1);
    }
    __syncthreads();

    for (int idx = tid; idx < K_ * 25; idx += 256) {
        int e = idx / 25, g2 = idx - e * 25;
        float dx = sAI[PA_[g2]*3+0] - sAJ[e][PB_[g2]*3+0];
        float dy = sAI[PA_[g2]*3+1] - sAJ[e][PB_[g2]*3+1];
        float dz = sAI[PA_[g2]*3+2] - sAJ[e][PB_[g2]*3+2];
        sDist[e][g2] = sqrtf(dx*dx + dy*dy + dz*dz + 1e-6f);
    }
    __syncthreads();

    // fill x (bf16), 2 features per thread-step
    for (int idx = tid; idx < K_ * (EDGE_IN_ / 2); idx += 256) {
        int e  = idx / (EDGE_IN_ / 2);
        int cc = (idx - e * (EDGE_IN_ / 2)) * 2;
        float v0, v1;
        if (cc < NPE_) {
            int dp = sDpos[e];
            v0 = pe_w[dp * NPE_ + cc]     + pe_b[cc];
            v1 = pe_w[dp * NPE_ + cc + 1] + pe_b[cc + 1];
        } else {
            int g2 = (cc - NPE_) >> 4;
            int r0 = (cc - NPE_) & 15;
            float dist = sDist[e][g2];
            float t0 = (dist - (2.0f + (20.0f/15.0f) * r0)) * 0.8f;
            float t1 = (dist - (2.0f + (20.0f/15.0f) * (r0+1))) * 0.8f;
            v0 = __expf(-t0 * t0);
            v1 = __expf(-t1 * t1);
        }
        unsigned pk = (unsigned)f2bf(v0) | ((unsigned)f2bf(v1) << 16);
        *(unsigned*)&xb[e * XB_STRIDE + cc] = pk;
    }
    __syncthreads();

    // ---- MFMA GEMM: [48 x 416] x [416 x 128] ----
    int wv = tid >> 6;
    int ln = tid & 63;
    int lr = ln & 15;
    int lg = ln >> 4;

    f32x4 acc[3][2];
    #pragma unroll
    for (int rf = 0; rf < 3; ++rf)
        #pragma unroll
        for (int cf = 0; cf < 2; ++cf)
            acc[rf][cf] = (f32x4){0.0f, 0.0f, 0.0f, 0.0f};

    const unsigned short* wbase_h0 = wt_h + (size_t)(wv*32 + lr) * EDGE_IN_ + lg*8;
    const unsigned short* wbase_h1 = wt_h + (size_t)(wv*32 + 16 + lr) * EDGE_IN_ + lg*8;
    const unsigned short* wbase_l0 = wt_l + (size_t)(wv*32 + lr) * EDGE_IN_ + lg*8;
    const unsigned short* wbase_l1 = wt_l + (size_t)(wv*32 + 16 + lr) * EDGE_IN_ + lg*8;

    #pragma unroll 1
    for (int ks = 0; ks < EDGE_IN_ / 32; ++ks) {
        int k0 = ks * 32;
        bf16x8 a[3], bh[2], bl[2];
        #pragma unroll
        for (int rf = 0; rf < 3; ++rf)
            a[rf] = *(const bf16x8*)&xb[(rf*16 + lr) * XB_STRIDE + k0 + lg*8];
        bh[0] = *(const bf16x8*)(wbase_h0 + k0);
        bh[1] = *(const bf16x8*)(wbase_h1 + k0);
        bl[0] = *(const bf16x8*)(wbase_l0 + k0);
        bl[1] = *(const bf16x8*)(wbase_l1 + k0);
        #pragma unroll
        for (int rf = 0; rf < 3; ++rf) {
            #pragma unroll
            for (int cf = 0; cf < 2; ++cf) {
                acc[rf][cf] = __builtin_amdgcn_mfma_f32_16x16x32_bf16(a[rf], bh[cf], acc[rf][cf], 0, 0, 0);
                acc[rf][cf] = __builtin_amdgcn_mfma_f32_16x16x32_bf16(a[rf], bl[cf], acc[rf][cf], 0, 0, 0);
            }
        }
    }
    __syncthreads();   // all waves done reading xb; sBuf becomes sE

    #pragma unroll
    for (int rf = 0; rf < 3; ++rf)
        #pragma unroll
        for (int cf = 0; cf < 2; ++cf)
            #pragma unroll
            for (int r = 0; r < 4; ++r) {
                int row = rf*16 + lg*4 + r;
                int col = wv*32 + cf*16 + lr;
                sE[row * SE_STRIDE + col] = acc[rf][cf][r];
            }
    __syncthreads();

    // LayerNorm: 16 lanes per edge, 8 features per lane; 3 passes of 16 edges
    int l16 = tid & 15;
    float gv[8], bv[8];
    #pragma unroll
    for (int q = 0; q < 8; ++q) { gv[q] = ne_g[l16*8 + q]; bv[q] = ne_b[l16*8 + q]; }

    for (int p = 0; p < 3; ++p) {
        int e = p*16 + (tid >> 4);
        float vals[8];
        #pragma unroll
        for (int q = 0; q < 8; ++q) vals[q] = sE[e * SE_STRIDE + l16*8 + q];
        float sum = 0.0f;
        #pragma unroll
        for (int q = 0; q < 8; ++q) sum += vals[q];
        #pragma unroll
        for (int m = 1; m < 16; m <<= 1) sum += __shfl_xor(sum, m, 64);
        float mu = sum * (1.0f / 128.0f);
        float s2 = 0.0f;
        #pragma unroll
        for (int q = 0; q < 8; ++q) { float d = vals[q] - mu; s2 += d * d; }
        #pragma unroll
        for (int m = 1; m < 16; m <<= 1) s2 += __shfl_xor(s2, m, 64);
        float rstd = rsqrtf(s2 * (1.0f / 128.0f) + 1e-5f);

        float* dst = out + E_OFF + (size_t)(gi * K_ + e) * EF_ + l16*8;
        #pragma unroll
        for (int q = 0; q < 8; ++q)
            dst[q] = (vals[q] - mu) * rstd * gv[q] + bv[q];
    }
}

extern "C" void kernel_launch(void* const* d_in, const int* in_sizes, int n_in,
                              void* d_out, int out_size, void* d_ws, size_t ws_size,
                              hipStream_t stream)
{
    const float* X      = (const float*)d_in[0];
    const float* mask   = (const float*)d_in[1];
    const int*   Ridx   = (const int*)d_in[2];
    const int*   chains = (const int*)d_in[3];
    const int*   memb   = (const int*)d_in[4];
    const float* pe_w   = (const float*)d_in[5];
    const float* pe_b   = (const float*)d_in[6];
    const float* edge_w = (const float*)d_in[7];
    const float* ne_g   = (const float*)d_in[8];
    const float* ne_b   = (const float*)d_in[9];
    const float* node_w = (const float*)d_in[10];
    const float* nn_g   = (const float*)d_in[11];
    const float* nn_b   = (const float*)d_in[12];
    float* out = (float*)d_out;

    unsigned short* wt_h = (unsigned short*)d_ws;
    unsigned short* wt_l = wt_h + (size_t)EDGE_IN_ * EF_;

    wprep_kernel<<<(EDGE_IN_*EF_ + 255)/256, 256, 0, stream>>>(edge_w, wt_h, wt_l);
    v_kernel<<<B_*L_, 128, 0, stream>>>(memb, node_w, nn_g, nn_b, out);
    topk_kernel<<<B_*L_, 256, 0, stream>>>(X, mask, out);
    edge_kernel<<<B_*L_, 256, 0, stream>>>(X, Ridx, chains, pe_w, pe_b,
                                           wt_h, wt_l, ne_g, ne_b, out);
}

// Round 5
// 212.003 us; speedup vs baseline: 3.1195x; 1.1654x over previous
//
#include <hip/hip_runtime.h>
#include <math.h>

#define B_ 4
#define L_ 1024
#define K_ 48
#define EF_ 128
#define NF_ 128
#define NPE_ 16
#define NRBF_ 16
#define MAXREL_ 32
#define EDGE_IN_ 416   // NPE + NRBF*25

#define V_SIZE   (B_*L_*NF_)          // 524288
#define E_OFF    (V_SIZE)
#define E_SIZE   (B_*L_*K_*EF_)       // 25165824
#define EIDX_OFF (E_OFF + E_SIZE)     // 25690112

#define XB_STRIDE 424                 // bf16 elems per x row (416 + 8 pad)
#define SE_STRIDE 132                 // f32 elems per E row (128 + 4 pad)

typedef __attribute__((ext_vector_type(8))) short bf16x8;
typedef __attribute__((ext_vector_type(4))) float f32x4;

// atom order: N=0, Ca=1, C=2, O=3, Cb=4. Group 0 = (Ca,Ca), then the 24 PAIRS.
__device__ const int PA_[25] = {1, 0,2,3,4, 1,1,1,1, 0,0,0, 4,4, 3, 0,2,3,4, 2,3,4, 2,3, 2};
__device__ const int PB_[25] = {1, 0,2,3,4, 0,2,3,4, 2,3,4, 2,3, 2, 1,1,1,1, 0,0,0, 4,4, 3};

__device__ __forceinline__ unsigned short f2bf(float f){   // RNE float->bf16
    unsigned u = __float_as_uint(f);
    unsigned r = u + 0x7fffu + ((u >> 16) & 1u);
    return (unsigned short)(r >> 16);
}

// ---------------- weight prep: fp32 [416][128] -> bf16 transposed [128][416] ----------------
__global__ __launch_bounds__(256) void wprep_kernel(const float* __restrict__ w,
                                                    unsigned short* __restrict__ wt)
{
    int idx = blockIdx.x * 256 + threadIdx.x;
    if (idx >= EDGE_IN_ * EF_) return;
    int f = idx & 127;
    int k = idx >> 7;
    wt[f * EDGE_IN_ + k] = f2bf(w[k * EF_ + f]);
}

// ---------------- V = LN(node_w[label]) ----------------
__global__ __launch_bounds__(128) void v_kernel(const int* __restrict__ labels,
                                                const float* __restrict__ node_w,
                                                const float* __restrict__ g,
                                                const float* __restrict__ bb,
                                                float* __restrict__ out)
{
    int gi = blockIdx.x;
    int f  = threadIdx.x;
    int lbl = labels[gi];
    float v = node_w[lbl*NF_ + f];

    __shared__ float red[2];
    __shared__ float red2[2];
    float s = v;
    #pragma unroll
    for (int m = 1; m < 64; m <<= 1) s += __shfl_xor(s, m, 64);
    if ((f & 63) == 0) red[f >> 6] = s;
    __syncthreads();
    float mu = (red[0] + red[1]) * (1.0f / NF_);
    float d = v - mu;
    float s2 = d * d;
    #pragma unroll
    for (int m = 1; m < 64; m <<= 1) s2 += __shfl_xor(s2, m, 64);
    if ((f & 63) == 0) red2[f >> 6] = s2;
    __syncthreads();
    float var = (red2[0] + red2[1]) * (1.0f / NF_);
    out[gi*NF_ + f] = d * rsqrtf(var + 1e-5f) * g[f] + bb[f];
}

// ---------------- top-K neighbor selection via full LDS bitonic sort ----------------
__global__ __launch_bounds__(256) void topk_kernel(const float* __restrict__ X,
                                                   const float* __restrict__ mask,
                                                   float* __restrict__ out)
{
    // keys[] (8KB) aliases the sCa staging buffer (12KB) — sCa is dead once
    // distances are computed.
    __shared__ __align__(16) unsigned char sMem[L_ * 3 * 4];
    __shared__ float sM[L_];
    __shared__ float sD[L_];
    __shared__ float wmax[4];

    float* sCa = (float*)sMem;
    unsigned long long* keys = (unsigned long long*)sMem;

    int gi = blockIdx.x;
    int b  = gi >> 10;
    int i  = gi & (L_ - 1);
    int tid = threadIdx.x;

    for (int idx = tid; idx < L_ * 3; idx += 256) {
        int j = idx / 3, d = idx - j * 3;
        sCa[idx] = X[(((size_t)((b << 10) + j)) * 4 + 1) * 3 + d];
    }
    for (int j = tid; j < L_; j += 256) sM[j] = mask[(b << 10) + j];
    __syncthreads();

    float cx = sCa[i*3+0], cy = sCa[i*3+1], cz = sCa[i*3+2];
    float mi = sM[i];
    float lmax = 0.0f;
    #pragma unroll
    for (int q = 0; q < 4; ++q) {
        int j = tid + q * 256;
        float dx = cx - sCa[j*3+0];
        float dy = cy - sCa[j*3+1];
        float dz = cz - sCa[j*3+2];
        float dist = sqrtf(dx*dx + dy*dy + dz*dz + 1e-6f);
        float D = mi * sM[j] * dist;
        sD[j] = D;
        lmax = fmaxf(lmax, D);
    }
    #pragma unroll
    for (int m = 1; m < 64; m <<= 1) lmax = fmaxf(lmax, __shfl_xor(lmax, m, 64));
    if ((tid & 63) == 0) wmax[tid >> 6] = lmax;
    __syncthreads();          // also: all sCa reads done before keys overwrite
    float Dmax = fmaxf(fmaxf(wmax[0], wmax[1]), fmaxf(wmax[2], wmax[3]));

    #pragma unroll
    for (int q = 0; q < 4; ++q) {
        int j = tid + q * 256;
        float m2 = mi * sM[j];
        float Dadj = sD[j] + (1.0f - m2) * Dmax;
        keys[j] = (((unsigned long long)__float_as_uint(Dadj)) << 32) | (unsigned)j;
    }

    // ascending bitonic sort of keys[0..1023]
    for (unsigned k = 2; k <= (unsigned)L_; k <<= 1) {
        for (unsigned j = k >> 1; j > 0; j >>= 1) {
            __syncthreads();
            #pragma unroll
            for (int q = 0; q < 4; ++q) {
                int idx = tid + q * 256;
                int l = idx ^ (int)j;
                if (l > idx) {
                    unsigned long long a = keys[idx];
                    unsigned long long c = keys[l];
                    bool asc = ((idx & (int)k) == 0);
                    if ((a > c) == asc) { keys[idx] = c; keys[l] = a; }
                }
            }
        }
    }
    __syncthreads();

    if (tid < K_)
        out[EIDX_OFF + (size_t)gi * K_ + tid] = (float)(unsigned)(keys[tid] & 0xffffffffULL);
}

// ---------------- edge features + MFMA matmul + LN ----------------
// One block = one residue = 48 edges. 4 waves; wave w owns 32 feature cols.
__global__ __launch_bounds__(256) void edge_kernel(const float* __restrict__ X,
                                                   const int* __restrict__ Ridx,
                                                   const int* __restrict__ chains,
                                                   const float* __restrict__ pe_w,
                                                   const float* __restrict__ pe_b,
                                                   const unsigned short* __restrict__ wt,
                                                   const float* __restrict__ ne_g,
                                                   const float* __restrict__ ne_b,
                                                   float* __restrict__ out)
{
    __shared__ float sAI[16];
    __shared__ float sAJ[K_][16];
    __shared__ int   sJ[K_];
    __shared__ int   sDpos[K_];
    __shared__ float sDist[K_][26];
    __shared__ __align__(16) unsigned char sBuf[K_ * XB_STRIDE * 2];  // xb (bf16) then reused as sE (f32)

    unsigned short* xb = (unsigned short*)sBuf;
    float* sE = (float*)sBuf;

    int tid = threadIdx.x;
    int gi  = blockIdx.x;          // residue index in [0, B*L)
    int b   = gi >> 10;
    int i   = gi & (L_ - 1);

    if (tid < K_) sJ[tid] = (int)out[EIDX_OFF + (size_t)gi * K_ + tid];
    __syncthreads();

    // per-edge neighbor atoms (+Cb) and the i-residue atoms
    if (tid < K_ + 1) {
        int r = (tid < K_) ? sJ[tid] : i;
        const float* xr = X + ((size_t)((b << 10) + r)) * 12;
        float n0=xr[0],  n1=xr[1],  n2=xr[2];
        float a0=xr[3],  a1=xr[4],  a2=xr[5];
        float c0=xr[6],  c1=xr[7],  c2=xr[8];
        float o0=xr[9],  o1=xr[10], o2=xr[11];
        float bx=a0-n0, by=a1-n1, bz=a2-n2;
        float vx=c0-a0, vy=c1-a1, vz=c2-a2;
        float ax = by*vz - bz*vy;
        float ay = bz*vx - bx*vz;
        float az = bx*vy - by*vx;
        float cb0 = -0.58273431f*ax + 0.56802827f*bx - 0.54067466f*vx + a0;
        float cb1 = -0.58273431f*ay + 0.56802827f*by - 0.54067466f*vy + a1;
        float cb2 = -0.58273431f*az + 0.56802827f*bz - 0.54067466f*vz + a2;
        float* dst = (tid < K_) ? &sAJ[tid][0] : &sAI[0];
        dst[0]=n0;  dst[1]=n1;  dst[2]=n2;
        dst[3]=a0;  dst[4]=a1;  dst[5]=a2;
        dst[6]=c0;  dst[7]=c1;  dst[8]=c2;
        dst[9]=o0;  dst[10]=o1; dst[11]=o2;
        dst[12]=cb0; dst[13]=cb1; dst[14]=cb2;
    }
    if (tid >= 64 && tid < 64 + K_) {
        int e = tid - 64;
        int j = sJ[e];
        int off  = Ridx[gi] - Ridx[(b << 10) + j];
        int same = (chains[gi] == chains[(b << 10) + j]);
        int dcl = off + MAXREL_;
        dcl = dcl < 0 ? 0 : (dcl > 2*MAXREL_ ? 2*MAXREL_ : dcl);
        sDpos[e] = same ? dcl : (2*MAXREL_ + 1);
    }
    __syncthreads();

    for (int idx = tid; idx < K_ * 25; idx += 256) {
        int e = idx / 25, g2 = idx - e * 25;
        float dx = sAI[PA_[g2]*3+0] - sAJ[e][PB_[g2]*3+0];
        float dy = sAI[PA_[g2]*3+1] - sAJ[e][PB_[g2]*3+1];
        float dz = sAI[PA_[g2]*3+2] - sAJ[e][PB_[g2]*3+2];
        sDist[e][g2] = sqrtf(dx*dx + dy*dy + dz*dz + 1e-6f);
    }
    __syncthreads();

    // fill x (bf16), 2 features per thread-step
    for (int idx = tid; idx < K_ * (EDGE_IN_ / 2); idx += 256) {
        int e  = idx / (EDGE_IN_ / 2);
        int cc = (idx - e * (EDGE_IN_ / 2)) * 2;
        float v0, v1;
        if (cc < NPE_) {
            int dp = sDpos[e];
            v0 = pe_w[dp * NPE_ + cc]     + pe_b[cc];
            v1 = pe_w[dp * NPE_ + cc + 1] + pe_b[cc + 1];
        } else {
            int g2 = (cc - NPE_) >> 4;
            int r0 = (cc - NPE_) & 15;
            float dist = sDist[e][g2];
            float t0 = (dist - (2.0f + (20.0f/15.0f) * r0)) * 0.8f;
            float t1 = (dist - (2.0f + (20.0f/15.0f) * (r0+1))) * 0.8f;
            v0 = __expf(-t0 * t0);
            v1 = __expf(-t1 * t1);
        }
        unsigned pk = (unsigned)f2bf(v0) | ((unsigned)f2bf(v1) << 16);
        *(unsigned*)&xb[e * XB_STRIDE + cc] = pk;
    }
    __syncthreads();

    // ---- MFMA GEMM: [48 x 416] x [416 x 128] ----
    int wv = tid >> 6;
    int ln = tid & 63;
    int lr = ln & 15;
    int lg = ln >> 4;

    f32x4 acc[3][2];
    #pragma unroll
    for (int rf = 0; rf < 3; ++rf)
        #pragma unroll
        for (int cf = 0; cf < 2; ++cf)
            acc[rf][cf] = (f32x4){0.0f, 0.0f, 0.0f, 0.0f};

    const unsigned short* wbase0 = wt + (size_t)(wv*32 + lr) * EDGE_IN_ + lg*8;
    const unsigned short* wbase1 = wt + (size_t)(wv*32 + 16 + lr) * EDGE_IN_ + lg*8;

    #pragma unroll 4
    for (int ks = 0; ks < EDGE_IN_ / 32; ++ks) {
        int k0 = ks * 32;
        bf16x8 a[3], bh[2];
        bh[0] = *(const bf16x8*)(wbase0 + k0);
        bh[1] = *(const bf16x8*)(wbase1 + k0);
        #pragma unroll
        for (int rf = 0; rf < 3; ++rf)
            a[rf] = *(const bf16x8*)&xb[(rf*16 + lr) * XB_STRIDE + k0 + lg*8];
        #pragma unroll
        for (int rf = 0; rf < 3; ++rf) {
            #pragma unroll
            for (int cf = 0; cf < 2; ++cf)
                acc[rf][cf] = __builtin_amdgcn_mfma_f32_16x16x32_bf16(a[rf], bh[cf], acc[rf][cf], 0, 0, 0);
        }
    }
    __syncthreads();   // all waves done reading xb; sBuf becomes sE

    #pragma unroll
    for (int rf = 0; rf < 3; ++rf)
        #pragma unroll
        for (int cf = 0; cf < 2; ++cf)
            #pragma unroll
            for (int r = 0; r < 4; ++r) {
                int row = rf*16 + lg*4 + r;
                int col = wv*32 + cf*16 + lr;
                sE[row * SE_STRIDE + col] = acc[rf][cf][r];
            }
    __syncthreads();

    // LayerNorm: 16 lanes per edge, 8 features per lane; 3 passes of 16 edges
    int l16 = tid & 15;
    float gv[8], bv[8];
    #pragma unroll
    for (int q = 0; q < 8; ++q) { gv[q] = ne_g[l16*8 + q]; bv[q] = ne_b[l16*8 + q]; }

    for (int p = 0; p < 3; ++p) {
        int e = p*16 + (tid >> 4);
        float vals[8];
        #pragma unroll
        for (int q = 0; q < 8; ++q) vals[q] = sE[e * SE_STRIDE + l16*8 + q];
        float sum = 0.0f;
        #pragma unroll
        for (int q = 0; q < 8; ++q) sum += vals[q];
        #pragma unroll
        for (int m = 1; m < 16; m <<= 1) sum += __shfl_xor(sum, m, 64);
        float mu = sum * (1.0f / 128.0f);
        float s2 = 0.0f;
        #pragma unroll
        for (int q = 0; q < 8; ++q) { float d = vals[q] - mu; s2 += d * d; }
        #pragma unroll
        for (int m = 1; m < 16; m <<= 1) s2 += __shfl_xor(s2, m, 64);
        float rstd = rsqrtf(s2 * (1.0f / 128.0f) + 1e-5f);

        float* dst = out + E_OFF + (size_t)(gi * K_ + e) * EF_ + l16*8;
        f32x4 o0, o1;
        o0[0] = (vals[0] - mu) * rstd * gv[0] + bv[0];
        o0[1] = (vals[1] - mu) * rstd * gv[1] + bv[1];
        o0[2] = (vals[2] - mu) * rstd * gv[2] + bv[2];
        o0[3] = (vals[3] - mu) * rstd * gv[3] + bv[3];
        o1[0] = (vals[4] - mu) * rstd * gv[4] + bv[4];
        o1[1] = (vals[5] - mu) * rstd * gv[5] + bv[5];
        o1[2] = (vals[6] - mu) * rstd * gv[6] + bv[6];
        o1[3] = (vals[7] - mu) * rstd * gv[7] + bv[7];
        __builtin_nontemporal_store(o0, (f32x4*)dst);
        __builtin_nontemporal_store(o1, (f32x4*)(dst + 4));
    }
}

extern "C" void kernel_launch(void* const* d_in, const int* in_sizes, int n_in,
                              void* d_out, int out_size, void* d_ws, size_t ws_size,
                              hipStream_t stream)
{
    const float* X      = (const float*)d_in[0];
    const float* mask   = (const float*)d_in[1];
    const int*   Ridx   = (const int*)d_in[2];
    const int*   chains = (const int*)d_in[3];
    const int*   memb   = (const int*)d_in[4];
    const float* pe_w   = (const float*)d_in[5];
    const float* pe_b   = (const float*)d_in[6];
    const float* edge_w = (const float*)d_in[7];
    const float* ne_g   = (const float*)d_in[8];
    const float* ne_b   = (const float*)d_in[9];
    const float* node_w = (const float*)d_in[10];
    const float* nn_g   = (const float*)d_in[11];
    const float* nn_b   = (const float*)d_in[12];
    float* out = (float*)d_out;

    unsigned short* wt = (unsigned short*)d_ws;

    wprep_kernel<<<(EDGE_IN_*EF_ + 255)/256, 256, 0, stream>>>(edge_w, wt);
    v_kernel<<<B_*L_, 128, 0, stream>>>(memb, node_w, nn_g, nn_b, out);
    topk_kernel<<<B_*L_, 256, 0, stream>>>(X, mask, out);
    edge_kernel<<<B_*L_, 256, 0, stream>>>(X, Ridx, chains, pe_w, pe_b,
                                           wt, ne_g, ne_b, out);
}

// Round 6
// 139.799 us; speedup vs baseline: 4.7307x; 1.5165x over previous
//
#include <hip/hip_runtime.h>
#include <math.h>

#define B_ 4
#define L_ 1024
#define K_ 48
#define EF_ 128
#define NF_ 128
#define NPE_ 16
#define NRBF_ 16
#define MAXREL_ 32
#define EDGE_IN_ 416   // NPE + NRBF*25

#define V_SIZE   (B_*L_*NF_)          // 524288
#define E_OFF    (V_SIZE)
#define E_SIZE   (B_*L_*K_*EF_)       // 25165824
#define EIDX_OFF (E_OFF + E_SIZE)     // 25690112

#define XB_STRIDE 424                 // bf16 elems per x row (416 + 8 pad)
#define SE_STRIDE 132                 // f32 elems per E row (128 + 4 pad)

typedef __attribute__((ext_vector_type(8))) short bf16x8;
typedef __attribute__((ext_vector_type(4))) float f32x4;

// atom order: N=0, Ca=1, C=2, O=3, Cb=4. Group 0 = (Ca,Ca), then the 24 PAIRS.
__device__ const int PA_[25] = {1, 0,2,3,4, 1,1,1,1, 0,0,0, 4,4, 3, 0,2,3,4, 2,3,4, 2,3, 2};
__device__ const int PB_[25] = {1, 0,2,3,4, 0,2,3,4, 2,3,4, 2,3, 2, 1,1,1,1, 0,0,0, 4,4, 3};

__device__ __forceinline__ unsigned short f2bf(float f){   // RNE float->bf16
    unsigned u = __float_as_uint(f);
    unsigned r = u + 0x7fffu + ((u >> 16) & 1u);
    return (unsigned short)(r >> 16);
}

// ---------------- weight prep: fp32 [416][128] -> bf16 transposed [128][416] ----------------
__global__ __launch_bounds__(256) void wprep_kernel(const float* __restrict__ w,
                                                    unsigned short* __restrict__ wt)
{
    int idx = blockIdx.x * 256 + threadIdx.x;
    if (idx >= EDGE_IN_ * EF_) return;
    int f = idx & 127;
    int k = idx >> 7;
    wt[f * EDGE_IN_ + k] = f2bf(w[k * EF_ + f]);
}

// ---------------- V = LN(node_w[label]) ----------------
__global__ __launch_bounds__(128) void v_kernel(const int* __restrict__ labels,
                                                const float* __restrict__ node_w,
                                                const float* __restrict__ g,
                                                const float* __restrict__ bb,
                                                float* __restrict__ out)
{
    int gi = blockIdx.x;
    int f  = threadIdx.x;
    int lbl = labels[gi];
    float v = node_w[lbl*NF_ + f];

    __shared__ float red[2];
    __shared__ float red2[2];
    float s = v;
    #pragma unroll
    for (int m = 1; m < 64; m <<= 1) s += __shfl_xor(s, m, 64);
    if ((f & 63) == 0) red[f >> 6] = s;
    __syncthreads();
    float mu = (red[0] + red[1]) * (1.0f / NF_);
    float d = v - mu;
    float s2 = d * d;
    #pragma unroll
    for (int m = 1; m < 64; m <<= 1) s2 += __shfl_xor(s2, m, 64);
    if ((f & 63) == 0) red2[f >> 6] = s2;
    __syncthreads();
    float var = (red2[0] + red2[1]) * (1.0f / NF_);
    out[gi*NF_ + f] = d * rsqrtf(var + 1e-5f) * g[f] + bb[f];
}

// ---------------- top-K neighbor selection via u64 MSB radix-select ----------------
// key = (float_bits(Dadj) << 32) | j  — unique per j, ascending order == jax top_k order.
__global__ __launch_bounds__(256) void topk_kernel(const float* __restrict__ X,
                                                   const float* __restrict__ mask,
                                                   float* __restrict__ out)
{
    __shared__ float sCa[L_ * 3];          // 12 KB
    __shared__ float sM[L_];               // 4 KB
    __shared__ unsigned hist[256];         // 1 KB (counts, then inclusive cums)
    __shared__ float wmax[4];
    __shared__ int sSelBin;
    __shared__ unsigned sSelLo;
    __shared__ unsigned long long cand[K_];
    __shared__ unsigned sCnt;

    int gi = blockIdx.x;
    int b  = gi >> 10;
    int i  = gi & (L_ - 1);
    int tid = threadIdx.x;

    for (int idx = tid; idx < L_ * 3; idx += 256) {
        int j = idx / 3, d = idx - j * 3;
        sCa[idx] = X[(((size_t)((b << 10) + j)) * 4 + 1) * 3 + d];
    }
    for (int j = tid; j < L_; j += 256) sM[j] = mask[(b << 10) + j];
    if (tid == 0) sCnt = 0;
    __syncthreads();

    float cx = sCa[i*3+0], cy = sCa[i*3+1], cz = sCa[i*3+2];
    float mi = sM[i];

    // pass A: row max of D
    float lmax = 0.0f;
    #pragma unroll
    for (int q = 0; q < 4; ++q) {
        int j = tid + q * 256;
        float dx = cx - sCa[j*3+0];
        float dy = cy - sCa[j*3+1];
        float dz = cz - sCa[j*3+2];
        float dist = sqrtf(dx*dx + dy*dy + dz*dz + 1e-6f);
        lmax = fmaxf(lmax, mi * sM[j] * dist);
    }
    #pragma unroll
    for (int m = 1; m < 64; m <<= 1) lmax = fmaxf(lmax, __shfl_xor(lmax, m, 64));
    if ((tid & 63) == 0) wmax[tid >> 6] = lmax;
    __syncthreads();
    float Dmax = fmaxf(fmaxf(wmax[0], wmax[1]), fmaxf(wmax[2], wmax[3]));

    // build keys in registers
    unsigned long long key[4];
    bool act[4];
    #pragma unroll
    for (int q = 0; q < 4; ++q) {
        int j = tid + q * 256;
        float dx = cx - sCa[j*3+0];
        float dy = cy - sCa[j*3+1];
        float dz = cz - sCa[j*3+2];
        float dist = sqrtf(dx*dx + dy*dy + dz*dz + 1e-6f);
        float m2 = mi * sM[j];
        float Dadj = m2 * dist + (1.0f - m2) * Dmax;
        key[q] = (((unsigned long long)__float_as_uint(Dadj)) << 32) | (unsigned)j;
        act[q] = true;
    }

    // MSB radix-select for rank 47 (0-based). Key bytes [31:16] are always 0 -> 6 passes.
    unsigned r = K_ - 1;
    unsigned long long T = 0;
    const int shifts[6] = {56, 48, 40, 32, 8, 0};
    #pragma unroll 1
    for (int p = 0; p < 6; ++p) {
        int sh = shifts[p];
        hist[tid] = 0;
        __syncthreads();
        #pragma unroll
        for (int q = 0; q < 4; ++q)
            if (act[q]) atomicAdd(&hist[(unsigned)((key[q] >> sh) & 255ULL)], 1u);
        __syncthreads();
        // one-wave inclusive scan of 256 bins (4 bins/lane)
        if (tid < 64) {
            unsigned b0 = hist[tid*4+0], b1 = hist[tid*4+1], b2 = hist[tid*4+2], b3 = hist[tid*4+3];
            unsigned s0 = b0, s1 = s0 + b1, s2 = s1 + b2, s3 = s2 + b3;
            unsigned s = s3;
            #pragma unroll
            for (int m = 1; m < 64; m <<= 1) {
                unsigned o = __shfl_up(s, m, 64);
                if (tid >= m) s += o;
            }
            unsigned base = s - s3;
            hist[tid*4+0] = base + s0;
            hist[tid*4+1] = base + s1;
            hist[tid*4+2] = base + s2;
            hist[tid*4+3] = base + s3;
        }
        __syncthreads();
        unsigned lo = (tid == 0) ? 0u : hist[tid - 1];
        unsigned hi = hist[tid];
        if (r >= lo && r < hi) { sSelBin = tid; sSelLo = lo; }
        __syncthreads();
        int bsel = sSelBin;
        r -= sSelLo;
        T |= ((unsigned long long)(unsigned)bsel) << sh;
        #pragma unroll
        for (int q = 0; q < 4; ++q)
            act[q] = act[q] && ((unsigned)((key[q] >> sh) & 255ULL) == (unsigned)bsel);
        __syncthreads();   // protect hist/sSel before next pass re-zero
    }

    // exactly 48 keys <= T (keys unique)
    #pragma unroll
    for (int q = 0; q < 4; ++q)
        if (key[q] <= T) {
            unsigned pos = atomicAdd(&sCnt, 1u);
            cand[pos] = key[q];
        }
    __syncthreads();

    // wave 0: in-register bitonic sort of 64 (48 real + pad), emit ascending
    if (tid < 64) {
        unsigned long long k64 = (tid < K_) ? cand[tid] : 0xffffffffffffffffULL;
        #pragma unroll
        for (unsigned kk = 2; kk <= 64; kk <<= 1) {
            #pragma unroll
            for (unsigned jj = kk >> 1; jj > 0; jj >>= 1) {
                unsigned long long o = __shfl_xor(k64, jj, 64);
                bool lower = (tid & jj) == 0;
                bool asc   = (tid & kk) == 0;
                unsigned long long mn = (k64 < o) ? k64 : o;
                unsigned long long mx = (k64 < o) ? o : k64;
                k64 = (lower == asc) ? mn : mx;
            }
        }
        if (tid < K_)
            out[EIDX_OFF + (size_t)gi * K_ + tid] = (float)(unsigned)(k64 & 0xffffffffULL);
    }
}

// ---------------- edge features + MFMA matmul + LN ----------------
// One block = one residue = 48 edges. 4 waves; wave w owns 32 feature cols.
__global__ __launch_bounds__(256) void edge_kernel(const float* __restrict__ X,
                                                   const int* __restrict__ Ridx,
                                                   const int* __restrict__ chains,
                                                   const float* __restrict__ pe_w,
                                                   const float* __restrict__ pe_b,
                                                   const unsigned short* __restrict__ wt,
                                                   const float* __restrict__ ne_g,
                                                   const float* __restrict__ ne_b,
                                                   float* __restrict__ out)
{
    __shared__ float sAI[16];
    __shared__ float sAJ[K_][16];
    __shared__ int   sJ[K_];
    __shared__ int   sDpos[K_];
    __shared__ float sDist[K_][26];
    __shared__ __align__(16) unsigned char sBuf[K_ * XB_STRIDE * 2];  // xb (bf16) then reused as sE (f32)

    unsigned short* xb = (unsigned short*)sBuf;
    float* sE = (float*)sBuf;

    int tid = threadIdx.x;
    int gi  = blockIdx.x;          // residue index in [0, B*L)
    int b   = gi >> 10;
    int i   = gi & (L_ - 1);

    if (tid < K_) sJ[tid] = (int)out[EIDX_OFF + (size_t)gi * K_ + tid];
    __syncthreads();

    // per-edge neighbor atoms (+Cb) and the i-residue atoms
    if (tid < K_ + 1) {
        int r = (tid < K_) ? sJ[tid] : i;
        const float* xr = X + ((size_t)((b << 10) + r)) * 12;
        float n0=xr[0],  n1=xr[1],  n2=xr[2];
        float a0=xr[3],  a1=xr[4],  a2=xr[5];
        float c0=xr[6],  c1=xr[7],  c2=xr[8];
        float o0=xr[9],  o1=xr[10], o2=xr[11];
        float bx=a0-n0, by=a1-n1, bz=a2-n2;
        float vx=c0-a0, vy=c1-a1, vz=c2-a2;
        float ax = by*vz - bz*vy;
        float ay = bz*vx - bx*vz;
        float az = bx*vy - by*vx;
        float cb0 = -0.58273431f*ax + 0.56802827f*bx - 0.54067466f*vx + a0;
        float cb1 = -0.58273431f*ay + 0.56802827f*by - 0.54067466f*vy + a1;
        float cb2 = -0.58273431f*az + 0.56802827f*bz - 0.54067466f*vz + a2;
        float* dst = (tid < K_) ? &sAJ[tid][0] : &sAI[0];
        dst[0]=n0;  dst[1]=n1;  dst[2]=n2;
        dst[3]=a0;  dst[4]=a1;  dst[5]=a2;
        dst[6]=c0;  dst[7]=c1;  dst[8]=c2;
        dst[9]=o0;  dst[10]=o1; dst[11]=o2;
        dst[12]=cb0; dst[13]=cb1; dst[14]=cb2;
    }
    if (tid >= 64 && tid < 64 + K_) {
        int e = tid - 64;
        int j = sJ[e];
        int off  = Ridx[gi] - Ridx[(b << 10) + j];
        int same = (chains[gi] == chains[(b << 10) + j]);
        int dcl = off + MAXREL_;
        dcl = dcl < 0 ? 0 : (dcl > 2*MAXREL_ ? 2*MAXREL_ : dcl);
        sDpos[e] = same ? dcl : (2*MAXREL_ + 1);
    }
    __syncthreads();

    for (int idx = tid; idx < K_ * 25; idx += 256) {
        int e = idx / 25, g2 = idx - e * 25;
        float dx = sAI[PA_[g2]*3+0] - sAJ[e][PB_[g2]*3+0];
        float dy = sAI[PA_[g2]*3+1] - sAJ[e][PB_[g2]*3+1];
        float dz = sAI[PA_[g2]*3+2] - sAJ[e][PB_[g2]*3+2];
        sDist[e][g2] = sqrtf(dx*dx + dy*dy + dz*dz + 1e-6f);
    }
    __syncthreads();

    // fill x (bf16), 2 features per thread-step
    for (int idx = tid; idx < K_ * (EDGE_IN_ / 2); idx += 256) {
        int e  = idx / (EDGE_IN_ / 2);
        int cc = (idx - e * (EDGE_IN_ / 2)) * 2;
        float v0, v1;
        if (cc < NPE_) {
            int dp = sDpos[e];
            v0 = pe_w[dp * NPE_ + cc]     + pe_b[cc];
            v1 = pe_w[dp * NPE_ + cc + 1] + pe_b[cc + 1];
        } else {
            int g2 = (cc - NPE_) >> 4;
            int r0 = (cc - NPE_) & 15;
            float dist = sDist[e][g2];
            float t0 = (dist - (2.0f + (20.0f/15.0f) * r0)) * 0.8f;
            float t1 = (dist - (2.0f + (20.0f/15.0f) * (r0+1))) * 0.8f;
            v0 = __expf(-t0 * t0);
            v1 = __expf(-t1 * t1);
        }
        unsigned pk = (unsigned)f2bf(v0) | ((unsigned)f2bf(v1) << 16);
        *(unsigned*)&xb[e * XB_STRIDE + cc] = pk;
    }
    __syncthreads();

    // ---- MFMA GEMM: [48 x 416] x [416 x 128] ----
    int wv = tid >> 6;
    int ln = tid & 63;
    int lr = ln & 15;
    int lg = ln >> 4;

    f32x4 acc[3][2];
    #pragma unroll
    for (int rf = 0; rf < 3; ++rf)
        #pragma unroll
        for (int cf = 0; cf < 2; ++cf)
            acc[rf][cf] = (f32x4){0.0f, 0.0f, 0.0f, 0.0f};

    const unsigned short* wbase0 = wt + (size_t)(wv*32 + lr) * EDGE_IN_ + lg*8;
    const unsigned short* wbase1 = wt + (size_t)(wv*32 + 16 + lr) * EDGE_IN_ + lg*8;

    #pragma unroll 4
    for (int ks = 0; ks < EDGE_IN_ / 32; ++ks) {
        int k0 = ks * 32;
        bf16x8 a[3], bh[2];
        bh[0] = *(const bf16x8*)(wbase0 + k0);
        bh[1] = *(const bf16x8*)(wbase1 + k0);
        #pragma unroll
        for (int rf = 0; rf < 3; ++rf)
            a[rf] = *(const bf16x8*)&xb[(rf*16 + lr) * XB_STRIDE + k0 + lg*8];
        #pragma unroll
        for (int rf = 0; rf < 3; ++rf) {
            #pragma unroll
            for (int cf = 0; cf < 2; ++cf)
                acc[rf][cf] = __builtin_amdgcn_mfma_f32_16x16x32_bf16(a[rf], bh[cf], acc[rf][cf], 0, 0, 0);
        }
    }
    __syncthreads();   // all waves done reading xb; sBuf becomes sE

    #pragma unroll
    for (int rf = 0; rf < 3; ++rf)
        #pragma unroll
        for (int cf = 0; cf < 2; ++cf)
            #pragma unroll
            for (int r = 0; r < 4; ++r) {
                int row = rf*16 + lg*4 + r;
                int col = wv*32 + cf*16 + lr;
                sE[row * SE_STRIDE + col] = acc[rf][cf][r];
            }
    __syncthreads();

    // LayerNorm: 16 lanes per edge, 8 features per lane; 3 passes of 16 edges
    int l16 = tid & 15;
    float gv[8], bv[8];
    #pragma unroll
    for (int q = 0; q < 8; ++q) { gv[q] = ne_g[l16*8 + q]; bv[q] = ne_b[l16*8 + q]; }

    for (int p = 0; p < 3; ++p) {
        int e = p*16 + (tid >> 4);
        float vals[8];
        #pragma unroll
        for (int q = 0; q < 8; ++q) vals[q] = sE[e * SE_STRIDE + l16*8 + q];
        float sum = 0.0f;
        #pragma unroll
        for (int q = 0; q < 8; ++q) sum += vals[q];
        #pragma unroll
        for (int m = 1; m < 16; m <<= 1) sum += __shfl_xor(sum, m, 64);
        float mu = sum * (1.0f / 128.0f);
        float s2 = 0.0f;
        #pragma unroll
        for (int q = 0; q < 8; ++q) { float d = vals[q] - mu; s2 += d * d; }
        #pragma unroll
        for (int m = 1; m < 16; m <<= 1) s2 += __shfl_xor(s2, m, 64);
        float rstd = rsqrtf(s2 * (1.0f / 128.0f) + 1e-5f);

        float* dst = out + E_OFF + (size_t)(gi * K_ + e) * EF_ + l16*8;
        f32x4 o0, o1;
        o0[0] = (vals[0] - mu) * rstd * gv[0] + bv[0];
        o0[1] = (vals[1] - mu) * rstd * gv[1] + bv[1];
        o0[2] = (vals[2] - mu) * rstd * gv[2] + bv[2];
        o0[3] = (vals[3] - mu) * rstd * gv[3] + bv[3];
        o1[0] = (vals[4] - mu) * rstd * gv[4] + bv[4];
        o1[1] = (vals[5] - mu) * rstd * gv[5] + bv[5];
        o1[2] = (vals[6] - mu) * rstd * gv[6] + bv[6];
        o1[3] = (vals[7] - mu) * rstd * gv[7] + bv[7];
        __builtin_nontemporal_store(o0, (f32x4*)dst);
        __builtin_nontemporal_store(o1, (f32x4*)(dst + 4));
    }
}

extern "C" void kernel_launch(void* const* d_in, const int* in_sizes, int n_in,
                              void* d_out, int out_size, void* d_ws, size_t ws_size,
                              hipStream_t stream)
{
    const float* X      = (const float*)d_in[0];
    const float* mask   = (const float*)d_in[1];
    const int*   Ridx   = (const int*)d_in[2];
    const int*   chains = (const int*)d_in[3];
    const int*   memb   = (const int*)d_in[4];
    const float* pe_w   = (const float*)d_in[5];
    const float* pe_b   = (const float*)d_in[6];
    const float* edge_w = (const float*)d_in[7];
    const float* ne_g   = (const float*)d_in[8];
    const float* ne_b   = (const float*)d_in[9];
    const float* node_w = (const float*)d_in[10];
    const float* nn_g   = (const float*)d_in[11];
    const float* nn_b   = (const float*)d_in[12];
    float* out = (float*)d_out;

    unsigned short* wt = (unsigned short*)d_ws;

    wprep_kernel<<<(EDGE_IN_*EF_ + 255)/256, 256, 0, stream>>>(edge_w, wt);
    v_kernel<<<B_*L_, 128, 0, stream>>>(memb, node_w, nn_g, nn_b, out);
    topk_kernel<<<B_*L_, 256, 0, stream>>>(X, mask, out);
    edge_kernel<<<B_*L_, 256, 0, stream>>>(X, Ridx, chains, pe_w, pe_b,
                                           wt, ne_g, ne_b, out);
}

// Round 8
// 101.867 us; speedup vs baseline: 6.4922x; 1.3724x over previous
//
#include <hip/hip_runtime.h>
#include <math.h>

#define B_ 4
#define L_ 1024
#define K_ 48
#define EF_ 128
#define NF_ 128
#define NPE_ 16
#define NRBF_ 16
#define MAXREL_ 32
#define EDGE_IN_ 416   // NPE + NRBF*25

#define V_SIZE   (B_*L_*NF_)          // 524288
#define E_OFF    (V_SIZE)
#define E_SIZE   (B_*L_*K_*EF_)       // 25165824
#define EIDX_OFF (E_OFF + E_SIZE)     // 25690112

#define XH_STRIDE 232                 // bf16 elems per half-row (224 + 8 pad)
#define SE_STRIDE 132                 // f32 elems per E row (128 + 4 pad)

typedef __attribute__((ext_vector_type(8))) short bf16x8;
typedef __attribute__((ext_vector_type(4))) float f32x4;
typedef __attribute__((ext_vector_type(4))) unsigned u32x4;

// atom order: N=0, Ca=1, C=2, O=3, Cb=4. Group 0 = (Ca,Ca), then the 24 PAIRS.
__device__ const int PA_[25] = {1, 0,2,3,4, 1,1,1,1, 0,0,0, 4,4, 3, 0,2,3,4, 2,3,4, 2,3, 2};
__device__ const int PB_[25] = {1, 0,2,3,4, 0,2,3,4, 2,3,4, 2,3, 2, 1,1,1,1, 0,0,0, 4,4, 3};

__device__ __forceinline__ unsigned short f2bf(float f){   // RNE float->bf16
    unsigned u = __float_as_uint(f);
    unsigned r = u + 0x7fffu + ((u >> 16) & 1u);
    return (unsigned short)(r >> 16);
}

// ---------------- weight prep: fp32 [416][128] -> bf16 transposed [128][416] ----------------
__global__ __launch_bounds__(256) void wprep_kernel(const float* __restrict__ w,
                                                    unsigned short* __restrict__ wt)
{
    int idx = blockIdx.x * 256 + threadIdx.x;
    if (idx >= EDGE_IN_ * EF_) return;
    int f = idx & 127;
    int k = idx >> 7;
    wt[f * EDGE_IN_ + k] = f2bf(w[k * EF_ + f]);
}

// ---------------- V = LN(node_w[label]) ----------------
__global__ __launch_bounds__(128) void v_kernel(const int* __restrict__ labels,
                                                const float* __restrict__ node_w,
                                                const float* __restrict__ g,
                                                const float* __restrict__ bb,
                                                float* __restrict__ out)
{
    int gi = blockIdx.x;
    int f  = threadIdx.x;
    int lbl = labels[gi];
    float v = node_w[lbl*NF_ + f];

    __shared__ float red[2];
    __shared__ float red2[2];
    float s = v;
    #pragma unroll
    for (int m = 1; m < 64; m <<= 1) s += __shfl_xor(s, m, 64);
    if ((f & 63) == 0) red[f >> 6] = s;
    __syncthreads();
    float mu = (red[0] + red[1]) * (1.0f / NF_);
    float d = v - mu;
    float s2 = d * d;
    #pragma unroll
    for (int m = 1; m < 64; m <<= 1) s2 += __shfl_xor(s2, m, 64);
    if ((f & 63) == 0) red2[f >> 6] = s2;
    __syncthreads();
    float var = (red2[0] + red2[1]) * (1.0f / NF_);
    out[gi*NF_ + f] = d * rsqrtf(var + 1e-5f) * g[f] + bb[f];
}

// ---------------- top-K neighbor selection via u64 MSB radix-select ----------------
// key = (float_bits(Dadj) << 32) | j  — unique per j, ascending order == jax top_k order.
__global__ __launch_bounds__(256) void topk_kernel(const float* __restrict__ X,
                                                   const float* __restrict__ mask,
                                                   float* __restrict__ out)
{
    __shared__ float sCa[L_ * 3];          // 12 KB
    __shared__ float sM[L_];               // 4 KB
    __shared__ unsigned hist[256];         // 1 KB (counts, then inclusive cums)
    __shared__ float wmax[4];
    __shared__ int sSelBin;
    __shared__ unsigned sSelLo;
    __shared__ unsigned long long cand[K_];
    __shared__ unsigned sCnt;

    int gi = blockIdx.x;
    int b  = gi >> 10;
    int i  = gi & (L_ - 1);
    int tid = threadIdx.x;

    for (int idx = tid; idx < L_ * 3; idx += 256) {
        int j = idx / 3, d = idx - j * 3;
        sCa[idx] = X[(((size_t)((b << 10) + j)) * 4 + 1) * 3 + d];
    }
    for (int j = tid; j < L_; j += 256) sM[j] = mask[(b << 10) + j];
    if (tid == 0) sCnt = 0;
    __syncthreads();

    float cx = sCa[i*3+0], cy = sCa[i*3+1], cz = sCa[i*3+2];
    float mi = sM[i];

    // pass A: row max of D
    float lmax = 0.0f;
    #pragma unroll
    for (int q = 0; q < 4; ++q) {
        int j = tid + q * 256;
        float dx = cx - sCa[j*3+0];
        float dy = cy - sCa[j*3+1];
        float dz = cz - sCa[j*3+2];
        float dist = sqrtf(dx*dx + dy*dy + dz*dz + 1e-6f);
        lmax = fmaxf(lmax, mi * sM[j] * dist);
    }
    #pragma unroll
    for (int m = 1; m < 64; m <<= 1) lmax = fmaxf(lmax, __shfl_xor(lmax, m, 64));
    if ((tid & 63) == 0) wmax[tid >> 6] = lmax;
    __syncthreads();
    float Dmax = fmaxf(fmaxf(wmax[0], wmax[1]), fmaxf(wmax[2], wmax[3]));

    // build keys in registers
    unsigned long long key[4];
    bool act[4];
    #pragma unroll
    for (int q = 0; q < 4; ++q) {
        int j = tid + q * 256;
        float dx = cx - sCa[j*3+0];
        float dy = cy - sCa[j*3+1];
        float dz = cz - sCa[j*3+2];
        float dist = sqrtf(dx*dx + dy*dy + dz*dz + 1e-6f);
        float m2 = mi * sM[j];
        float Dadj = m2 * dist + (1.0f - m2) * Dmax;
        key[q] = (((unsigned long long)__float_as_uint(Dadj)) << 32) | (unsigned)j;
        act[q] = true;
    }

    // MSB radix-select for rank 47 (0-based). Key bytes [31:16] are always 0 -> 6 passes.
    unsigned r = K_ - 1;
    unsigned long long T = 0;
    const int shifts[6] = {56, 48, 40, 32, 8, 0};
    #pragma unroll 1
    for (int p = 0; p < 6; ++p) {
        int sh = shifts[p];
        hist[tid] = 0;
        __syncthreads();
        #pragma unroll
        for (int q = 0; q < 4; ++q)
            if (act[q]) atomicAdd(&hist[(unsigned)((key[q] >> sh) & 255ULL)], 1u);
        __syncthreads();
        // one-wave inclusive scan of 256 bins (4 bins/lane)
        if (tid < 64) {
            unsigned b0 = hist[tid*4+0], b1 = hist[tid*4+1], b2 = hist[tid*4+2], b3 = hist[tid*4+3];
            unsigned s0 = b0, s1 = s0 + b1, s2 = s1 + b2, s3 = s2 + b3;
            unsigned s = s3;
            #pragma unroll
            for (int m = 1; m < 64; m <<= 1) {
                unsigned o = __shfl_up(s, m, 64);
                if (tid >= m) s += o;
            }
            unsigned base = s - s3;
            hist[tid*4+0] = base + s0;
            hist[tid*4+1] = base + s1;
            hist[tid*4+2] = base + s2;
            hist[tid*4+3] = base + s3;
        }
        __syncthreads();
        unsigned lo = (tid == 0) ? 0u : hist[tid - 1];
        unsigned hi = hist[tid];
        if (r >= lo && r < hi) { sSelBin = tid; sSelLo = lo; }
        __syncthreads();
        int bsel = sSelBin;
        r -= sSelLo;
        T |= ((unsigned long long)(unsigned)bsel) << sh;
        #pragma unroll
        for (int q = 0; q < 4; ++q)
            act[q] = act[q] && ((unsigned)((key[q] >> sh) & 255ULL) == (unsigned)bsel);
        __syncthreads();   // protect hist/sSel before next pass re-zero
    }

    // exactly 48 keys <= T (keys unique)
    #pragma unroll
    for (int q = 0; q < 4; ++q)
        if (key[q] <= T) {
            unsigned pos = atomicAdd(&sCnt, 1u);
            cand[pos] = key[q];
        }
    __syncthreads();

    // wave 0: in-register bitonic sort of 64 (48 real + pad), emit ascending
    if (tid < 64) {
        unsigned long long k64 = (tid < K_) ? cand[tid] : 0xffffffffffffffffULL;
        #pragma unroll
        for (unsigned kk = 2; kk <= 64; kk <<= 1) {
            #pragma unroll
            for (unsigned jj = kk >> 1; jj > 0; jj >>= 1) {
                unsigned long long o = __shfl_xor(k64, jj, 64);
                bool lower = (tid & jj) == 0;
                bool asc   = (tid & kk) == 0;
                unsigned long long mn = (k64 < o) ? k64 : o;
                unsigned long long mx = (k64 < o) ? o : k64;
                k64 = (lower == asc) ? mn : mx;
            }
        }
        if (tid < K_)
            out[EIDX_OFF + (size_t)gi * K_ + tid] = (float)(unsigned)(k64 & 0xffffffffULL);
    }
}

// ---------------- edge features + MFMA matmul + LN ----------------
// One block = one residue = 48 edges. 4 waves; wave w owns 32 feature cols.
// K-split: stage x cols [0,224) then [224,416) in one 22.3 KB half-buffer;
// accumulators persist in registers across the two halves.
__global__ __launch_bounds__(256, 5) void edge_kernel(const float* __restrict__ X,
                                                   const int* __restrict__ Ridx,
                                                   const int* __restrict__ chains,
                                                   const float* __restrict__ pe_w,
                                                   const float* __restrict__ pe_b,
                                                   const unsigned short* __restrict__ wt,
                                                   const float* __restrict__ ne_g,
                                                   const float* __restrict__ ne_b,
                                                   float* __restrict__ out)
{
    __shared__ float sAI[16];
    __shared__ float sAJ[K_][16];
    __shared__ int   sJ[K_];
    __shared__ int   sDpos[K_];
    // xh (48 x 232 bf16 = 22272 B) and sE (48 x 132 f32 = 25344 B) alias.
    __shared__ __align__(16) unsigned char sBuf[K_ * SE_STRIDE * 4];

    unsigned short* xh = (unsigned short*)sBuf;
    float* sE = (float*)sBuf;

    int tid = threadIdx.x;
    int gi  = blockIdx.x;          // residue index in [0, B*L)
    int b   = gi >> 10;
    int i   = gi & (L_ - 1);

    if (tid < K_) sJ[tid] = (int)out[EIDX_OFF + (size_t)gi * K_ + tid];
    __syncthreads();

    // per-edge neighbor atoms (+Cb) and the i-residue atoms
    if (tid < K_ + 1) {
        int r = (tid < K_) ? sJ[tid] : i;
        const float* xr = X + ((size_t)((b << 10) + r)) * 12;
        float n0=xr[0],  n1=xr[1],  n2=xr[2];
        float a0=xr[3],  a1=xr[4],  a2=xr[5];
        float c0=xr[6],  c1=xr[7],  c2=xr[8];
        float o0=xr[9],  o1=xr[10], o2=xr[11];
        float bx=a0-n0, by=a1-n1, bz=a2-n2;
        float vx=c0-a0, vy=c1-a1, vz=c2-a2;
        float ax = by*vz - bz*vy;
        float ay = bz*vx - bx*vz;
        float az = bx*vy - by*vx;
        float cb0 = -0.58273431f*ax + 0.56802827f*bx - 0.54067466f*vx + a0;
        float cb1 = -0.58273431f*ay + 0.56802827f*by - 0.54067466f*vy + a1;
        float cb2 = -0.58273431f*az + 0.56802827f*bz - 0.54067466f*vz + a2;
        float* dst = (tid < K_) ? &sAJ[tid][0] : &sAI[0];
        dst[0]=n0;  dst[1]=n1;  dst[2]=n2;
        dst[3]=a0;  dst[4]=a1;  dst[5]=a2;
        dst[6]=c0;  dst[7]=c1;  dst[8]=c2;
        dst[9]=o0;  dst[10]=o1; dst[11]=o2;
        dst[12]=cb0; dst[13]=cb1; dst[14]=cb2;
    }
    if (tid >= 64 && tid < 64 + K_) {
        int e = tid - 64;
        int j = sJ[e];
        int off  = Ridx[gi] - Ridx[(b << 10) + j];
        int same = (chains[gi] == chains[(b << 10) + j]);
        int dcl = off + MAXREL_;
        dcl = dcl < 0 ? 0 : (dcl > 2*MAXREL_ ? 2*MAXREL_ : dcl);
        sDpos[e] = same ? dcl : (2*MAXREL_ + 1);
    }
    __syncthreads();

    const int wv = tid >> 6;
    const int ln = tid & 63;
    const int lr = ln & 15;
    const int lg = ln >> 4;

    f32x4 acc[3][2];
    #pragma unroll
    for (int rf = 0; rf < 3; ++rf)
        #pragma unroll
        for (int cf = 0; cf < 2; ++cf)
            acc[rf][cf] = (f32x4){0.0f, 0.0f, 0.0f, 0.0f};

    const unsigned short* wbase0 = wt + (size_t)(wv*32 + lr) * EDGE_IN_ + lg*8;
    const unsigned short* wbase1 = wt + (size_t)(wv*32 + 16 + lr) * EDGE_IN_ + lg*8;

    #pragma unroll
    for (int h = 0; h < 2; ++h) {
        // ---- fill half-tile (dist folded in; bf16 pack via v_cvt_pk_bf16_f32) ----
        if (h == 0) {
            #pragma unroll
            for (int p = 0; p < 2; ++p) {  // PE block: 48 edges x 8 threads = 384 items
                int idx = tid + p * 256;
                if (idx < 384) {
                    int e = idx >> 3, cc = (idx & 7) * 2;
                    int dp = sDpos[e];
                    float v0 = pe_w[dp*NPE_ + cc]     + pe_b[cc];
                    float v1 = pe_w[dp*NPE_ + cc + 1] + pe_b[cc + 1];
                    unsigned pk;
                    asm("v_cvt_pk_bf16_f32 %0, %1, %2" : "=v"(pk) : "v"(v0), "v"(v1));
                    *(unsigned*)&xh[e * XH_STRIDE + cc] = pk;
                }
            }
            #pragma unroll
            for (int p = 0; p < 3; ++p) {  // RBF groups 0..12: 624 pairs
                int idx = tid + p * 256;
                if (idx < 624) {
                    int e = idx / 13, g2 = idx - e * 13;
                    float dx = sAI[PA_[g2]*3+0] - sAJ[e][PB_[g2]*3+0];
                    float dy = sAI[PA_[g2]*3+1] - sAJ[e][PB_[g2]*3+1];
                    float dz = sAI[PA_[g2]*3+2] - sAJ[e][PB_[g2]*3+2];
                    float dist = sqrtf(dx*dx + dy*dy + dz*dz + 1e-6f);
                    float t = 0.8f * dist - 1.6f;
                    unsigned pk[8];
                    #pragma unroll
                    for (int rr = 0; rr < 8; ++rr) {
                        float v0 = __expf(-t * t); t -= 1.06666672f;
                        float v1 = __expf(-t * t); t -= 1.06666672f;
                        asm("v_cvt_pk_bf16_f32 %0, %1, %2" : "=v"(pk[rr]) : "v"(v0), "v"(v1));
                    }
                    u32x4 w0 = {pk[0], pk[1], pk[2], pk[3]};
                    u32x4 w1 = {pk[4], pk[5], pk[6], pk[7]};
                    int cb = NPE_ + g2 * 16;
                    *(u32x4*)&xh[e * XH_STRIDE + cb]     = w0;
                    *(u32x4*)&xh[e * XH_STRIDE + cb + 8] = w1;
                }
            }
        } else {
            #pragma unroll
            for (int p = 0; p < 3; ++p) {  // RBF groups 13..24: 576 pairs
                int idx = tid + p * 256;
                if (idx < 576) {
                    int e = idx / 12, g2 = 13 + (idx - e * 12);
                    float dx = sAI[PA_[g2]*3+0] - sAJ[e][PB_[g2]*3+0];
                    float dy = sAI[PA_[g2]*3+1] - sAJ[e][PB_[g2]*3+1];
                    float dz = sAI[PA_[g2]*3+2] - sAJ[e][PB_[g2]*3+2];
                    float dist = sqrtf(dx*dx + dy*dy + dz*dz + 1e-6f);
                    float t = 0.8f * dist - 1.6f;
                    unsigned pk[8];
                    #pragma unroll
                    for (int rr = 0; rr < 8; ++rr) {
                        float v0 = __expf(-t * t); t -= 1.06666672f;
                        float v1 = __expf(-t * t); t -= 1.06666672f;
                        asm("v_cvt_pk_bf16_f32 %0, %1, %2" : "=v"(pk[rr]) : "v"(v0), "v"(v1));
                    }
                    u32x4 w0 = {pk[0], pk[1], pk[2], pk[3]};
                    u32x4 w1 = {pk[4], pk[5], pk[6], pk[7]};
                    int cb = (g2 - 13) * 16;   // global col 16+g2*16 - 224
                    *(u32x4*)&xh[e * XH_STRIDE + cb]     = w0;
                    *(u32x4*)&xh[e * XH_STRIDE + cb + 8] = w1;
                }
            }
        }
        __syncthreads();

        // ---- MFMA over this half's K range ----
        const int kb  = h ? 224 : 0;
        const int nks = h ? 6 : 7;
        #pragma unroll 4
        for (int ks = 0; ks < nks; ++ks) {
            int k0 = ks * 32;
            bf16x8 a[3], bh[2];
            bh[0] = *(const bf16x8*)(wbase0 + kb + k0);
            bh[1] = *(const bf16x8*)(wbase1 + kb + k0);
            #pragma unroll
            for (int rf = 0; rf < 3; ++rf)
                a[rf] = *(const bf16x8*)&xh[(rf*16 + lr) * XH_STRIDE + k0 + lg*8];
            #pragma unroll
            for (int rf = 0; rf < 3; ++rf) {
                #pragma unroll
                for (int cf = 0; cf < 2; ++cf)
                    acc[rf][cf] = __builtin_amdgcn_mfma_f32_16x16x32_bf16(a[rf], bh[cf], acc[rf][cf], 0, 0, 0);
            }
        }
        __syncthreads();   // xh dead: next half refill (h=0) or sE overwrite (h=1)
    }

    #pragma unroll
    for (int rf = 0; rf < 3; ++rf)
        #pragma unroll
        for (int cf = 0; cf < 2; ++cf)
            #pragma unroll
            for (int r = 0; r < 4; ++r) {
                int row = rf*16 + lg*4 + r;
                int col = wv*32 + cf*16 + lr;
                sE[row * SE_STRIDE + col] = acc[rf][cf][r];
            }
    __syncthreads();

    // LayerNorm: 16 lanes per edge, 8 features per lane; 3 passes of 16 edges
    int l16 = tid & 15;
    float gv[8], bv[8];
    #pragma unroll
    for (int q = 0; q < 8; ++q) { gv[q] = ne_g[l16*8 + q]; bv[q] = ne_b[l16*8 + q]; }

    for (int p = 0; p < 3; ++p) {
        int e = p*16 + (tid >> 4);
        float vals[8];
        #pragma unroll
        for (int q = 0; q < 8; ++q) vals[q] = sE[e * SE_STRIDE + l16*8 + q];
        float sum = 0.0f;
        #pragma unroll
        for (int q = 0; q < 8; ++q) sum += vals[q];
        #pragma unroll
        for (int m = 1; m < 16; m <<= 1) sum += __shfl_xor(sum, m, 64);
        float mu = sum * (1.0f / 128.0f);
        float s2 = 0.0f;
        #pragma unroll
        for (int q = 0; q < 8; ++q) { float d = vals[q] - mu; s2 += d * d; }
        #pragma unroll
        for (int m = 1; m < 16; m <<= 1) s2 += __shfl_xor(s2, m, 64);
        float rstd = rsqrtf(s2 * (1.0f / 128.0f) + 1e-5f);

        float* dst = out + E_OFF + (size_t)(gi * K_ + e) * EF_ + l16*8;
        f32x4 o0, o1;
        o0[0] = (vals[0] - mu) * rstd * gv[0] + bv[0];
        o0[1] = (vals[1] - mu) * rstd * gv[1] + bv[1];
        o0[2] = (vals[2] - mu) * rstd * gv[2] + bv[2];
        o0[3] = (vals[3] - mu) * rstd * gv[3] + bv[3];
        o1[0] = (vals[4] - mu) * rstd * gv[4] + bv[4];
        o1[1] = (vals[5] - mu) * rstd * gv[5] + bv[5];
        o1[2] = (vals[6] - mu) * rstd * gv[6] + bv[6];
        o1[3] = (vals[7] - mu) * rstd * gv[7] + bv[7];
        __builtin_nontemporal_store(o0, (f32x4*)dst);
        __builtin_nontemporal_store(o1, (f32x4*)(dst + 4));
    }
}

extern "C" void kernel_launch(void* const* d_in, const int* in_sizes, int n_in,
                              void* d_out, int out_size, void* d_ws, size_t ws_size,
                              hipStream_t stream)
{
    const float* X      = (const float*)d_in[0];
    const float* mask   = (const float*)d_in[1];
    const int*   Ridx   = (const int*)d_in[2];
    const int*   chains = (const int*)d_in[3];
    const int*   memb   = (const int*)d_in[4];
    const float* pe_w   = (const float*)d_in[5];
    const float* pe_b   = (const float*)d_in[6];
    const float* edge_w = (const float*)d_in[7];
    const float* ne_g   = (const float*)d_in[8];
    const float* ne_b   = (const float*)d_in[9];
    const float* node_w = (const float*)d_in[10];
    const float* nn_g   = (const float*)d_in[11];
    const float* nn_b   = (const float*)d_in[12];
    float* out = (float*)d_out;

    unsigned short* wt = (unsigned short*)d_ws;

    wprep_kernel<<<(EDGE_IN_*EF_ + 255)/256, 256, 0, stream>>>(edge_w, wt);
    v_kernel<<<B_*L_, 128, 0, stream>>>(memb, node_w, nn_g, nn_b, out);
    topk_kernel<<<B_*L_, 256, 0, stream>>>(X, mask, out);
    edge_kernel<<<B_*L_, 256, 0, stream>>>(X, Ridx, chains, pe_w, pe_b,
                                           wt, ne_g, ne_b, out);
}

// Round 9
// 97.847 us; speedup vs baseline: 6.7590x; 1.0411x over previous
//
#include <hip/hip_runtime.h>
#include <math.h>

#define B_ 4
#define L_ 1024
#define K_ 48
#define EF_ 128
#define NF_ 128
#define NPE_ 16
#define NRBF_ 16
#define MAXREL_ 32
#define EDGE_IN_ 416   // NPE + NRBF*25

#define V_SIZE   (B_*L_*NF_)          // 524288
#define E_OFF    (V_SIZE)
#define E_SIZE   (B_*L_*K_*EF_)       // 25165824
#define EIDX_OFF (E_OFF + E_SIZE)     // 25690112

#define XH_STRIDE 232                 // bf16 elems per half-row (224 + 8 pad)
#define SE_STRIDE 132                 // f32 elems per E row (128 + 4 pad)

typedef __attribute__((ext_vector_type(8))) short bf16x8;
typedef __attribute__((ext_vector_type(4))) float f32x4;
typedef __attribute__((ext_vector_type(4))) unsigned u32x4;

// atom order: N=0, Ca=1, C=2, O=3, Cb=4. Group 0 = (Ca,Ca), then the 24 PAIRS.
__device__ const int PA_[25] = {1, 0,2,3,4, 1,1,1,1, 0,0,0, 4,4, 3, 0,2,3,4, 2,3,4, 2,3, 2};
__device__ const int PB_[25] = {1, 0,2,3,4, 0,2,3,4, 2,3,4, 2,3, 2, 1,1,1,1, 0,0,0, 4,4, 3};

__device__ __forceinline__ unsigned short f2bf(float f){   // RNE float->bf16
    unsigned u = __float_as_uint(f);
    unsigned r = u + 0x7fffu + ((u >> 16) & 1u);
    return (unsigned short)(r >> 16);
}

// ---------------- weight prep: fp32 [416][128] -> bf16 transposed [128][416] ----------------
__global__ __launch_bounds__(256) void wprep_kernel(const float* __restrict__ w,
                                                    unsigned short* __restrict__ wt)
{
    int idx = blockIdx.x * 256 + threadIdx.x;
    if (idx >= EDGE_IN_ * EF_) return;
    int f = idx & 127;
    int k = idx >> 7;
    wt[f * EDGE_IN_ + k] = f2bf(w[k * EF_ + f]);
}

// ---------------- V = LN(node_w[label]) ----------------
__global__ __launch_bounds__(128) void v_kernel(const int* __restrict__ labels,
                                                const float* __restrict__ node_w,
                                                const float* __restrict__ g,
                                                const float* __restrict__ bb,
                                                float* __restrict__ out)
{
    int gi = blockIdx.x;
    int f  = threadIdx.x;
    int lbl = labels[gi];
    float v = node_w[lbl*NF_ + f];

    __shared__ float red[2];
    __shared__ float red2[2];
    float s = v;
    #pragma unroll
    for (int m = 1; m < 64; m <<= 1) s += __shfl_xor(s, m, 64);
    if ((f & 63) == 0) red[f >> 6] = s;
    __syncthreads();
    float mu = (red[0] + red[1]) * (1.0f / NF_);
    float d = v - mu;
    float s2 = d * d;
    #pragma unroll
    for (int m = 1; m < 64; m <<= 1) s2 += __shfl_xor(s2, m, 64);
    if ((f & 63) == 0) red2[f >> 6] = s2;
    __syncthreads();
    float var = (red2[0] + red2[1]) * (1.0f / NF_);
    out[gi*NF_ + f] = d * rsqrtf(var + 1e-5f) * g[f] + bb[f];
}

// ---------------- fused: top-K select + edge features + MFMA + LN ----------------
// One block = one residue. Phase 1: u64 radix-select top-48 (early-exit when the
// rank-47 bin is a singleton). Phase 2: edge features + K-split MFMA + LN.
// sBuf aliases: {sCa 12K + sM 4K} -> {xh 22.3K} -> {sE 25.3K}.
__global__ __launch_bounds__(256, 5) void fused_kernel(const float* __restrict__ X,
                                                   const float* __restrict__ mask,
                                                   const int* __restrict__ Ridx,
                                                   const int* __restrict__ chains,
                                                   const float* __restrict__ pe_w,
                                                   const float* __restrict__ pe_b,
                                                   const unsigned short* __restrict__ wt,
                                                   const float* __restrict__ ne_g,
                                                   const float* __restrict__ ne_b,
                                                   float* __restrict__ out)
{
    __shared__ __align__(16) unsigned char sBuf[K_ * SE_STRIDE * 4];  // 25344 B
    float* sCa = (float*)sBuf;                       // [3072] phase 1
    float* sM  = (float*)(sBuf + 12288);             // [1024] phase 1
    unsigned short* xh = (unsigned short*)sBuf;      // phase 2 staging
    float* sE = (float*)sBuf;                        // phase 2 epilogue

    __shared__ float sAI[16];
    __shared__ float sAJ[K_][16];
    __shared__ int   sJ[K_];
    __shared__ int   sDpos[K_];
    __shared__ unsigned hist[256];
    __shared__ float wmax[4];
    __shared__ int sSelBin;
    __shared__ unsigned sSelLo, sSelCnt;
    __shared__ unsigned long long sTkey;
    __shared__ unsigned long long cand[K_];
    __shared__ unsigned sCnt;

    int tid = threadIdx.x;
    int gi  = blockIdx.x;          // residue index in [0, B*L)
    int b   = gi >> 10;
    int i   = gi & (L_ - 1);

    // ================= phase 1: top-K =================
    for (int idx = tid; idx < L_ * 3; idx += 256) {
        int j = idx / 3, d = idx - j * 3;
        sCa[idx] = X[(((size_t)((b << 10) + j)) * 4 + 1) * 3 + d];
    }
    for (int j = tid; j < L_; j += 256) sM[j] = mask[(b << 10) + j];
    if (tid == 0) sCnt = 0;
    __syncthreads();

    float cx = sCa[i*3+0], cy = sCa[i*3+1], cz = sCa[i*3+2];
    float mi = sM[i];

    float lmax = 0.0f;
    #pragma unroll
    for (int q = 0; q < 4; ++q) {
        int j = tid + q * 256;
        float dx = cx - sCa[j*3+0];
        float dy = cy - sCa[j*3+1];
        float dz = cz - sCa[j*3+2];
        float dist = sqrtf(dx*dx + dy*dy + dz*dz + 1e-6f);
        lmax = fmaxf(lmax, mi * sM[j] * dist);
    }
    #pragma unroll
    for (int m = 1; m < 64; m <<= 1) lmax = fmaxf(lmax, __shfl_xor(lmax, m, 64));
    if ((tid & 63) == 0) wmax[tid >> 6] = lmax;
    __syncthreads();
    float Dmax = fmaxf(fmaxf(wmax[0], wmax[1]), fmaxf(wmax[2], wmax[3]));

    unsigned long long key[4];
    bool act[4];
    #pragma unroll
    for (int q = 0; q < 4; ++q) {
        int j = tid + q * 256;
        float dx = cx - sCa[j*3+0];
        float dy = cy - sCa[j*3+1];
        float dz = cz - sCa[j*3+2];
        float dist = sqrtf(dx*dx + dy*dy + dz*dz + 1e-6f);
        float m2 = mi * sM[j];
        float Dadj = m2 * dist + (1.0f - m2) * Dmax;
        key[q] = (((unsigned long long)__float_as_uint(Dadj)) << 32) | (unsigned)j;
        act[q] = true;
    }

    // MSB radix-select for rank 47. Key bytes [31:16] always 0 -> <=6 passes.
    unsigned r = K_ - 1;
    unsigned long long T = 0;
    const int shifts[6] = {56, 48, 40, 32, 8, 0};
    #pragma unroll 1
    for (int p = 0; p < 6; ++p) {
        int sh = shifts[p];
        hist[tid] = 0;
        __syncthreads();
        #pragma unroll
        for (int q = 0; q < 4; ++q)
            if (act[q]) atomicAdd(&hist[(unsigned)((key[q] >> sh) & 255ULL)], 1u);
        __syncthreads();
        if (tid < 64) {   // one-wave inclusive scan of 256 bins
            unsigned b0 = hist[tid*4+0], b1 = hist[tid*4+1], b2 = hist[tid*4+2], b3 = hist[tid*4+3];
            unsigned s0 = b0, s1 = s0 + b1, s2 = s1 + b2, s3 = s2 + b3;
            unsigned s = s3;
            #pragma unroll
            for (int m = 1; m < 64; m <<= 1) {
                unsigned o = __shfl_up(s, m, 64);
                if (tid >= m) s += o;
            }
            unsigned base = s - s3;
            hist[tid*4+0] = base + s0;
            hist[tid*4+1] = base + s1;
            hist[tid*4+2] = base + s2;
            hist[tid*4+3] = base + s3;
        }
        __syncthreads();
        unsigned lo = (tid == 0) ? 0u : hist[tid - 1];
        unsigned hi = hist[tid];
        if (r >= lo && r < hi) { sSelBin = tid; sSelLo = lo; sSelCnt = hi - lo; }
        __syncthreads();
        int bsel = sSelBin;
        r -= sSelLo;
        T |= ((unsigned long long)(unsigned)bsel) << sh;
        #pragma unroll
        for (int q = 0; q < 4; ++q)
            act[q] = act[q] && ((unsigned)((key[q] >> sh) & 255ULL) == (unsigned)bsel);
        if (sSelCnt == 1) {        // unique survivor = exact rank-47 key
            #pragma unroll
            for (int q = 0; q < 4; ++q)
                if (act[q]) sTkey = key[q];
            __syncthreads();
            T = sTkey;
            break;
        }
        __syncthreads();   // protect hist/sSel before next pass re-zero
    }

    // exactly 48 keys <= T (keys unique)
    #pragma unroll
    for (int q = 0; q < 4; ++q)
        if (key[q] <= T) {
            unsigned pos = atomicAdd(&sCnt, 1u);
            cand[pos] = key[q];
        }
    __syncthreads();

    // wave 0: in-register bitonic sort of 64 (48 real + pad), emit ascending
    if (tid < 64) {
        unsigned long long k64 = (tid < K_) ? cand[tid] : 0xffffffffffffffffULL;
        #pragma unroll
        for (unsigned kk = 2; kk <= 64; kk <<= 1) {
            #pragma unroll
            for (unsigned jj = kk >> 1; jj > 0; jj >>= 1) {
                unsigned long long o = __shfl_xor(k64, jj, 64);
                bool lower = (tid & jj) == 0;
                bool asc   = (tid & kk) == 0;
                unsigned long long mn = (k64 < o) ? k64 : o;
                unsigned long long mx = (k64 < o) ? o : k64;
                k64 = (lower == asc) ? mn : mx;
            }
        }
        if (tid < K_) {
            int j = (int)(unsigned)(k64 & 0xffffffffULL);
            sJ[tid] = j;
            out[EIDX_OFF + (size_t)gi * K_ + tid] = (float)j;
        }
    }
    __syncthreads();

    // ================= phase 2: edge features + MFMA + LN =================
    if (tid < K_ + 1) {
        int rr = (tid < K_) ? sJ[tid] : i;
        const float* xr = X + ((size_t)((b << 10) + rr)) * 12;
        float n0=xr[0],  n1=xr[1],  n2=xr[2];
        float a0=xr[3],  a1=xr[4],  a2=xr[5];
        float c0=xr[6],  c1=xr[7],  c2=xr[8];
        float o0=xr[9],  o1=xr[10], o2=xr[11];
        float bx=a0-n0, by=a1-n1, bz=a2-n2;
        float vx=c0-a0, vy=c1-a1, vz=c2-a2;
        float ax = by*vz - bz*vy;
        float ay = bz*vx - bx*vz;
        float az = bx*vy - by*vx;
        float cb0 = -0.58273431f*ax + 0.56802827f*bx - 0.54067466f*vx + a0;
        float cb1 = -0.58273431f*ay + 0.56802827f*by - 0.54067466f*vy + a1;
        float cb2 = -0.58273431f*az + 0.56802827f*bz - 0.54067466f*vz + a2;
        float* dst = (tid < K_) ? &sAJ[tid][0] : &sAI[0];
        dst[0]=n0;  dst[1]=n1;  dst[2]=n2;
        dst[3]=a0;  dst[4]=a1;  dst[5]=a2;
        dst[6]=c0;  dst[7]=c1;  dst[8]=c2;
        dst[9]=o0;  dst[10]=o1; dst[11]=o2;
        dst[12]=cb0; dst[13]=cb1; dst[14]=cb2;
    }
    if (tid >= 64 && tid < 64 + K_) {
        int e = tid - 64;
        int j = sJ[e];
        int off  = Ridx[gi] - Ridx[(b << 10) + j];
        int same = (chains[gi] == chains[(b << 10) + j]);
        int dcl = off + MAXREL_;
        dcl = dcl < 0 ? 0 : (dcl > 2*MAXREL_ ? 2*MAXREL_ : dcl);
        sDpos[e] = same ? dcl : (2*MAXREL_ + 1);
    }
    __syncthreads();   // also: all sCa/sM reads done before xh overwrite

    const int wv = tid >> 6;
    const int ln = tid & 63;
    const int lr = ln & 15;
    const int lg = ln >> 4;

    f32x4 acc[3][2];
    #pragma unroll
    for (int rf = 0; rf < 3; ++rf)
        #pragma unroll
        for (int cf = 0; cf < 2; ++cf)
            acc[rf][cf] = (f32x4){0.0f, 0.0f, 0.0f, 0.0f};

    const unsigned short* wbase0 = wt + (size_t)(wv*32 + lr) * EDGE_IN_ + lg*8;
    const unsigned short* wbase1 = wt + (size_t)(wv*32 + 16 + lr) * EDGE_IN_ + lg*8;

    #pragma unroll
    for (int h = 0; h < 2; ++h) {
        if (h == 0) {
            #pragma unroll
            for (int p = 0; p < 2; ++p) {  // PE block: 48 edges x 8 threads = 384 items
                int idx = tid + p * 256;
                if (idx < 384) {
                    int e = idx >> 3, cc = (idx & 7) * 2;
                    int dp = sDpos[e];
                    float v0 = pe_w[dp*NPE_ + cc]     + pe_b[cc];
                    float v1 = pe_w[dp*NPE_ + cc + 1] + pe_b[cc + 1];
                    unsigned pk;
                    asm("v_cvt_pk_bf16_f32 %0, %1, %2" : "=v"(pk) : "v"(v0), "v"(v1));
                    *(unsigned*)&xh[e * XH_STRIDE + cc] = pk;
                }
            }
            #pragma unroll
            for (int p = 0; p < 3; ++p) {  // RBF groups 0..12: 624 pairs
                int idx = tid + p * 256;
                if (idx < 624) {
                    int e = idx / 13, g2 = idx - e * 13;
                    float dx = sAI[PA_[g2]*3+0] - sAJ[e][PB_[g2]*3+0];
                    float dy = sAI[PA_[g2]*3+1] - sAJ[e][PB_[g2]*3+1];
                    float dz = sAI[PA_[g2]*3+2] - sAJ[e][PB_[g2]*3+2];
                    float dist = sqrtf(dx*dx + dy*dy + dz*dz + 1e-6f);
                    float t = 0.8f * dist - 1.6f;
                    unsigned pk[8];
                    #pragma unroll
                    for (int rr = 0; rr < 8; ++rr) {
                        float v0 = __expf(-t * t); t -= 1.06666672f;
                        float v1 = __expf(-t * t); t -= 1.06666672f;
                        asm("v_cvt_pk_bf16_f32 %0, %1, %2" : "=v"(pk[rr]) : "v"(v0), "v"(v1));
                    }
                    u32x4 w0 = {pk[0], pk[1], pk[2], pk[3]};
                    u32x4 w1 = {pk[4], pk[5], pk[6], pk[7]};
                    int cb = NPE_ + g2 * 16;
                    *(u32x4*)&xh[e * XH_STRIDE + cb]     = w0;
                    *(u32x4*)&xh[e * XH_STRIDE + cb + 8] = w1;
                }
            }
        } else {
            #pragma unroll
            for (int p = 0; p < 3; ++p) {  // RBF groups 13..24: 576 pairs
                int idx = tid + p * 256;
                if (idx < 576) {
                    int e = idx / 12, g2 = 13 + (idx - e * 12);
                    float dx = sAI[PA_[g2]*3+0] - sAJ[e][PB_[g2]*3+0];
                    float dy = sAI[PA_[g2]*3+1] - sAJ[e][PB_[g2]*3+1];
                    float dz = sAI[PA_[g2]*3+2] - sAJ[e][PB_[g2]*3+2];
                    float dist = sqrtf(dx*dx + dy*dy + dz*dz + 1e-6f);
                    float t = 0.8f * dist - 1.6f;
                    unsigned pk[8];
                    #pragma unroll
                    for (int rr = 0; rr < 8; ++rr) {
                        float v0 = __expf(-t * t); t -= 1.06666672f;
                        float v1 = __expf(-t * t); t -= 1.06666672f;
                        asm("v_cvt_pk_bf16_f32 %0, %1, %2" : "=v"(pk[rr]) : "v"(v0), "v"(v1));
                    }
                    u32x4 w0 = {pk[0], pk[1], pk[2], pk[3]};
                    u32x4 w1 = {pk[4], pk[5], pk[6], pk[7]};
                    int cb = (g2 - 13) * 16;   // global col 16+g2*16 - 224
                    *(u32x4*)&xh[e * XH_STRIDE + cb]     = w0;
                    *(u32x4*)&xh[e * XH_STRIDE + cb + 8] = w1;
                }
            }
        }
        __syncthreads();

        const int kb  = h ? 224 : 0;
        const int nks = h ? 6 : 7;
        #pragma unroll 4
        for (int ks = 0; ks < nks; ++ks) {
            int k0 = ks * 32;
            bf16x8 a[3], bh[2];
            bh[0] = *(const bf16x8*)(wbase0 + kb + k0);
            bh[1] = *(const bf16x8*)(wbase1 + kb + k0);
            #pragma unroll
            for (int rf = 0; rf < 3; ++rf)
                a[rf] = *(const bf16x8*)&xh[(rf*16 + lr) * XH_STRIDE + k0 + lg*8];
            #pragma unroll
            for (int rf = 0; rf < 3; ++rf) {
                #pragma unroll
                for (int cf = 0; cf < 2; ++cf)
                    acc[rf][cf] = __builtin_amdgcn_mfma_f32_16x16x32_bf16(a[rf], bh[cf], acc[rf][cf], 0, 0, 0);
            }
        }
        __syncthreads();   // xh dead: next half refill (h=0) or sE overwrite (h=1)
    }

    #pragma unroll
    for (int rf = 0; rf < 3; ++rf)
        #pragma unroll
        for (int cf = 0; cf < 2; ++cf)
            #pragma unroll
            for (int r4 = 0; r4 < 4; ++r4) {
                int row = rf*16 + lg*4 + r4;
                int col = wv*32 + cf*16 + lr;
                sE[row * SE_STRIDE + col] = acc[rf][cf][r4];
            }
    __syncthreads();

    // LayerNorm: 16 lanes per edge, 8 features per lane; 3 passes of 16 edges
    int l16 = tid & 15;
    float gv[8], bv[8];
    #pragma unroll
    for (int q = 0; q < 8; ++q) { gv[q] = ne_g[l16*8 + q]; bv[q] = ne_b[l16*8 + q]; }

    for (int p = 0; p < 3; ++p) {
        int e = p*16 + (tid >> 4);
        float vals[8];
        #pragma unroll
        for (int q = 0; q < 8; ++q) vals[q] = sE[e * SE_STRIDE + l16*8 + q];
        float sum = 0.0f;
        #pragma unroll
        for (int q = 0; q < 8; ++q) sum += vals[q];
        #pragma unroll
        for (int m = 1; m < 16; m <<= 1) sum += __shfl_xor(sum, m, 64);
        float mu = sum * (1.0f / 128.0f);
        float s2 = 0.0f;
        #pragma unroll
        for (int q = 0; q < 8; ++q) { float d = vals[q] - mu; s2 += d * d; }
        #pragma unroll
        for (int m = 1; m < 16; m <<= 1) s2 += __shfl_xor(s2, m, 64);
        float rstd = rsqrtf(s2 * (1.0f / 128.0f) + 1e-5f);

        float* dst = out + E_OFF + (size_t)(gi * K_ + e) * EF_ + l16*8;
        f32x4 o0, o1;
        o0[0] = (vals[0] - mu) * rstd * gv[0] + bv[0];
        o0[1] = (vals[1] - mu) * rstd * gv[1] + bv[1];
        o0[2] = (vals[2] - mu) * rstd * gv[2] + bv[2];
        o0[3] = (vals[3] - mu) * rstd * gv[3] + bv[3];
        o1[0] = (vals[4] - mu) * rstd * gv[4] + bv[4];
        o1[1] = (vals[5] - mu) * rstd * gv[5] + bv[5];
        o1[2] = (vals[6] - mu) * rstd * gv[6] + bv[6];
        o1[3] = (vals[7] - mu) * rstd * gv[7] + bv[7];
        __builtin_nontemporal_store(o0, (f32x4*)dst);
        __builtin_nontemporal_store(o1, (f32x4*)(dst + 4));
    }
}

extern "C" void kernel_launch(void* const* d_in, const int* in_sizes, int n_in,
                              void* d_out, int out_size, void* d_ws, size_t ws_size,
                              hipStream_t stream)
{
    const float* X      = (const float*)d_in[0];
    const float* mask   = (const float*)d_in[1];
    const int*   Ridx   = (const int*)d_in[2];
    const int*   chains = (const int*)d_in[3];
    const int*   memb   = (const int*)d_in[4];
    const float* pe_w   = (const float*)d_in[5];
    const float* pe_b   = (const float*)d_in[6];
    const float* edge_w = (const float*)d_in[7];
    const float* ne_g   = (const float*)d_in[8];
    const float* ne_b   = (const float*)d_in[9];
    const float* node_w = (const float*)d_in[10];
    const float* nn_g   = (const float*)d_in[11];
    const float* nn_b   = (const float*)d_in[12];
    float* out = (float*)d_out;

    unsigned short* wt = (unsigned short*)d_ws;

    wprep_kernel<<<(EDGE_IN_*EF_ + 255)/256, 256, 0, stream>>>(edge_w, wt);
    v_kernel<<<B_*L_, 128, 0, stream>>>(memb, node_w, nn_g, nn_b, out);
    fused_kernel<<<B_*L_, 256, 0, stream>>>(X, mask, Ridx, chains, pe_w, pe_b,
                                            wt, ne_g, ne_b, out);
}